// Round 6
// baseline (806.847 us; speedup 1.0000x reference)
//
#include <hip/hip_runtime.h>
#include <hip/hip_fp16.h>
#include <math.h>

#define DD 256
#define NHEADS 8
#define HDIM 32
#define NLAYERS 2
#define GSZ 64
#define KGRID 4096      // GS*GS
#define TTASK 4
#define BB 4
#define NMEAS 511
#define SSRC 512        // N+1
#define HCITY 128
#define WCITY 128
#define ATT_SCALE 0.17677669529663687f   // 32^-0.5
#define INV2S2 78.125f                   // 1/(2*0.08^2)

typedef unsigned short u16;
typedef __attribute__((ext_vector_type(8))) short short8;
typedef __attribute__((ext_vector_type(4))) float f32x4;

__device__ __forceinline__ u16 f2bf(float f) {
    union { float f; unsigned int u; } x; x.f = f;
    return (u16)((x.u + 0x7fffu + ((x.u >> 16) & 1u)) >> 16);
}
__device__ __forceinline__ unsigned int pk2(float a, float b) {
    return (unsigned int)f2bf(a) | ((unsigned int)f2bf(b) << 16);
}
// HW packed f32->bf16 RNE (1 instr for 2 values)  [T12 recipe]
__device__ __forceinline__ unsigned int cvtpk_bf16(float a, float b) {
    unsigned int r;
    asm("v_cvt_pk_bf16_f32 %0, %1, %2" : "=v"(r) : "v"(a), "v"(b));
    return r;
}
// f16 (low 16 bits of u) -> f32
__device__ __forceinline__ float h2f(unsigned int u) {
    float r;
    asm("v_cvt_f32_f16 %0, %1" : "=v"(r) : "v"(u));
    return r;
}
__device__ __forceinline__ float gelu_f(float x) {
    return 0.5f * x * (1.0f + erff(x * 0.7071067811865476f));
}

// ---------------------------------------------------------------------------
__global__ void task_vec_kernel(const float* __restrict__ task_emb,
                                const float* __restrict__ tpW,
                                const float* __restrict__ tpb,
                                const int* __restrict__ task_id,
                                float* __restrict__ tv) {
    int b = blockIdx.x, t = threadIdx.x;
    int id = task_id[b];
    float a = tpb[t];
    for (int e = 0; e < DD; e++) a = fmaf(task_emb[id * DD + e], tpW[e * DD + t], a);
    tv[b * DD + t] = a;
}

__global__ void grid_init_kernel(const float* __restrict__ grid_pos,
                                 const float* __restrict__ tv,
                                 float* __restrict__ g) {
    int f = blockIdx.x * 256 + threadIdx.x;
    int b = f >> 18;
    float4 gp = ((const float4*)grid_pos)[f & 262143];
    float4 tvv = ((const float4*)tv)[b * 64 + (f & 63)];
    float4 o; o.x = gp.x + tvv.x; o.y = gp.y + tvv.y; o.z = gp.z + tvv.z; o.w = gp.w + tvv.w;
    ((float4*)g)[f] = o;
}

// ---------------------------------------------------------------------------
__global__ __launch_bounds__(256) void src_build_kernel(
    const float* __restrict__ meas_xy, const float* __restrict__ meas_v,
    const float* __restrict__ bs_xy, const float* __restrict__ city,
    const float* __restrict__ meas_W, const float* __restrict__ meas_b,
    const float* __restrict__ pW1, const float* __restrict__ pb1,
    const float* __restrict__ pW2, const float* __restrict__ pb2,
    const float* __restrict__ bs_W, const float* __restrict__ bs_b,
    float* __restrict__ src, float* __restrict__ src_xy) {
    __shared__ float sp[81];
    __shared__ float sh[DD];
    int b = blockIdx.x / SSRC, s = blockIdx.x % SSRC, t = threadIdx.x;
    if (s < NMEAS) {
        float mx = meas_xy[(b * NMEAS + s) * 2];
        float my = meas_xy[(b * NMEAS + s) * 2 + 1];
        float mv = meas_v[b * NMEAS + s];
        int cx = (int)rintf(mx * 127.0f); cx = min(max(cx, 0), 127);
        int cy = (int)rintf(my * 127.0f); cy = min(max(cy, 0), 127);
        if (t < 81) {
            int rr = cy + t / 9 - 4, cc = cx + t % 9 - 4;
            sp[t] = (rr >= 0 && rr < HCITY && cc >= 0 && cc < WCITY)
                        ? city[(b * HCITY + rr) * WCITY + cc] : 0.0f;
        }
        __syncthreads();
        float a1 = pb1[t];
        #pragma unroll 9
        for (int e = 0; e < 81; e++) a1 = fmaf(sp[e], pW1[e * DD + t], a1);
        sh[t] = gelu_f(a1);
        __syncthreads();
        float a2 = pb2[t];
        for (int e = 0; e < DD; e++) a2 = fmaf(sh[e], pW2[e * DD + t], a2);
        float mt = mx * meas_W[t] + my * meas_W[DD + t] + mv * meas_W[2 * DD + t] + meas_b[t];
        src[((size_t)(b * SSRC + s)) * DD + t] = mt + a2;
        if (t == 0) { src_xy[(b * SSRC + s) * 2] = mx; src_xy[(b * SSRC + s) * 2 + 1] = my; }
    } else {
        float bx = bs_xy[b * 2], by = bs_xy[b * 2 + 1];
        src[((size_t)(b * SSRC + s)) * DD + t] = bx * bs_W[t] + by * bs_W[DD + t] + bs_b[t];
        if (t == 0) { src_xy[(b * SSRC + s) * 2] = bx; src_xy[(b * SSRC + s) * 2 + 1] = by; }
    }
}

// ---------------------------------------------------------------------------
__global__ void density_kernel(const float* __restrict__ meas_xy, float* __restrict__ dens) {
    int w = threadIdx.x >> 6, lane = threadIdx.x & 63;
    int idx = blockIdx.x * 4 + w;
    int b = idx >> 12, k = idx & 4095;
    float gx = ((k & 63) + 0.5f) * (1.0f / 64.0f);
    float gy = ((k >> 6) + 0.5f) * (1.0f / 64.0f);
    float s = 0.0f;
    for (int n = lane; n < NMEAS; n += 64) {
        float2 xy = ((const float2*)meas_xy)[b * NMEAS + n];
        float dx = gx - xy.x, dy = gy - xy.y;
        s += __expf(-(dx * dx + dy * dy) * INV2S2);
    }
    #pragma unroll
    for (int o = 1; o < 64; o <<= 1) s += __shfl_xor(s, o, 64);
    if (lane == 0) dens[idx] = s * (1.0f / 511.0f);
}

// ---------------------------------------------------------------------------
// dist table: dt[b][k][s] = |gxy_k - src_xy[b][s]| as fp16 (RNE). 16.7 MB, L3-resident.
__global__ __launch_bounds__(256) void dist_kernel(const float* __restrict__ sxy_g,
                                                   u16* __restrict__ dt) {
    __shared__ float2 sxy[SSRC];
    int bk = blockIdx.x;             // b*4096 + k
    int b = bk >> 12, k = bk & 4095;
    int t = threadIdx.x;
    sxy[t]       = ((const float2*)sxy_g)[b * SSRC + t];
    sxy[t + 256] = ((const float2*)sxy_g)[b * SSRC + t + 256];
    __syncthreads();
    float gx = ((k & 63) + 0.5f) * (1.0f / 64.0f);
    float gy = ((k >> 6) + 0.5f) * (1.0f / 64.0f);
    float2 p0 = sxy[2 * t], p1 = sxy[2 * t + 1];
    float dx0 = gx - p0.x, dy0 = gy - p0.y;
    float dx1 = gx - p1.x, dy1 = gy - p1.y;
    float d0 = sqrtf(dx0 * dx0 + dy0 * dy0);
    float d1 = sqrtf(dx1 * dx1 + dy1 * dy1);
    __half h0 = __float2half(d0), h1 = __float2half(d1);   // RNE
    unsigned int pk = (unsigned int)__half_as_ushort(h0) |
                      ((unsigned int)__half_as_ushort(h1) << 16);
    ((unsigned int*)dt)[(size_t)bk * 256 + t] = pk;
}

// ---------------------------------------------------------------------------
// LayerNorm: one wave per row of 256; bf16 output.
__global__ void ln_kernel(const float* __restrict__ X, const float* __restrict__ g,
                          const float* __restrict__ bvec, u16* __restrict__ Yb, int rows) {
    int w = threadIdx.x >> 6, lane = threadIdx.x & 63;
    int row = blockIdx.x * 4 + w;
    if (row >= rows) return;
    float4 x = ((const float4*)X)[(size_t)row * 64 + lane];
    float s = x.x + x.y + x.z + x.w;
    float q = x.x * x.x + x.y * x.y + x.z * x.z + x.w * x.w;
    #pragma unroll
    for (int o = 1; o < 64; o <<= 1) { s += __shfl_xor(s, o, 64); q += __shfl_xor(q, o, 64); }
    float m = s * (1.0f / 256.0f);
    float v = q * (1.0f / 256.0f) - m * m;
    float rs = rsqrtf(v + 1e-5f);
    float4 gg = ((const float4*)g)[lane], bb = ((const float4*)bvec)[lane];
    float4 y;
    y.x = (x.x - m) * rs * gg.x + bb.x;
    y.y = (x.y - m) * rs * gg.y + bb.y;
    y.z = (x.z - m) * rs * gg.z + bb.z;
    y.w = (x.w - m) * rs * gg.w + bb.w;
    uint2 o2;
    o2.x = cvtpk_bf16(y.x, y.y);
    o2.y = cvtpk_bf16(y.z, y.w);
    *(uint2*)&Yb[(size_t)row * 256 + lane * 4] = o2;
}

// ---------------------------------------------------------------------------
// Weight convert: W[z][Kd][Nd] fp32 -> Wt[z][Nd][Kd] bf16 (32x32 LDS tiles).
__global__ __launch_bounds__(256) void wconv_kernel(const float* __restrict__ W,
                                                    u16* __restrict__ Wt, int Kd, int Nd) {
    __shared__ float L[32][33];
    int z = blockIdx.z;
    size_t zoff = (size_t)z * Kd * Nd;
    int n0 = blockIdx.x * 32, k0 = blockIdx.y * 32;
    int tx = threadIdx.x, ty = threadIdx.y;
    #pragma unroll
    for (int yy = 0; yy < 4; yy++)
        L[tx][ty + 8 * yy] = W[zoff + (size_t)(k0 + ty + 8 * yy) * Nd + n0 + tx];
    __syncthreads();
    #pragma unroll
    for (int yy = 0; yy < 4; yy++)
        Wt[zoff + (size_t)(n0 + ty + 8 * yy) * Kd + k0 + tx] = f2bf(L[ty + 8 * yy][tx]);
}

// V transpose: V[b*512+s][256] bf16 -> Vt[(b*256+n)][512] bf16.
__global__ __launch_bounds__(256) void vtrans_kernel(const u16* __restrict__ V,
                                                     u16* __restrict__ Vt) {
    __shared__ u16 L[32][33];
    int b = blockIdx.z;
    int n0 = blockIdx.x * 32, s0 = blockIdx.y * 32;
    int tx = threadIdx.x, ty = threadIdx.y;
    #pragma unroll
    for (int yy = 0; yy < 4; yy++)
        L[tx][ty + 8 * yy] = V[(size_t)(b * SSRC + s0 + ty + 8 * yy) * DD + n0 + tx];
    __syncthreads();
    #pragma unroll
    for (int yy = 0; yy < 4; yy++)
        Vt[(size_t)(b * DD + n0 + ty + 8 * yy) * SSRC + s0 + tx] = L[ty + 8 * yy][tx];
}

// ---------------------------------------------------------------------------
// bf16 MFMA GEMM: C = [res +] act(A @ Wt^T + bias). A[M][Kd] bf16, Wt[N][Kd] bf16.
// Block: 64 m-rows x 128 n-cols, 4 waves. KD compile-time -> unrolled, pipelined.
template <int ACT, int RES, int OBF, int OF32, int BATW, int KD>
__global__ __launch_bounds__(256) void gemm_mfma(
    const u16* __restrict__ A, const u16* __restrict__ Wt,
    const float* __restrict__ bias, float* __restrict__ C, u16* __restrict__ Cb,
    int M, int Nfull, const int* __restrict__ task_id, int wstride, int bstride) {
    int t = threadIdx.x;
    int w = t >> 6, lane = t & 63, lq = lane & 15, g = lane >> 4;
    int mblk = blockIdx.x * 64;
    int n0 = blockIdx.y * 128;
    const u16* Wp = Wt;
    const float* bp = bias;
    if (BATW) {
        int id = task_id[mblk / KGRID];
        Wp += (size_t)id * wstride;
        bp += (size_t)id * bstride;
    }
    const u16* Ap = A + (size_t)(mblk + w * 16 + lq) * KD + g * 8;
    const u16* Wr0 = Wp + (size_t)(n0 + lq) * KD + g * 8;
    f32x4 acc[8];
    #pragma unroll
    for (int nt = 0; nt < 8; nt++) acc[nt] = {0.f, 0.f, 0.f, 0.f};
    #pragma unroll 4
    for (int k = 0; k < KD; k += 32) {
        short8 af = *(const short8*)(Ap + k);
        #pragma unroll
        for (int nt = 0; nt < 8; nt++) {
            short8 wf = *(const short8*)(Wr0 + (size_t)nt * 16 * KD + k);
            acc[nt] = __builtin_amdgcn_mfma_f32_16x16x32_bf16(af, wf, acc[nt], 0, 0, 0);
        }
    }
    int mrow = mblk + w * 16 + 4 * g;
    #pragma unroll
    for (int nt = 0; nt < 8; nt++) {
        int col = n0 + nt * 16 + lq;
        float bv = bp[col];
        #pragma unroll
        for (int r = 0; r < 4; r++) {
            float o = acc[nt][r] + bv;
            if (ACT) o = gelu_f(o);
            size_t off = (size_t)(mrow + r) * Nfull + col;
            if (RES) o += C[off];
            if (OF32) C[off] = o;
            if (OBF) Cb[off] = f2bf(o);
        }
    }
}

// ---------------------------------------------------------------------------
// MFMA attention v3: dist from precomputed fp16 table; no sqrt/sxy in loop;
// P/O packing via v_cvt_pk_bf16_f32. Block = (b, kt, h) h-fastest; 4 waves x 16 q.
__global__ __launch_bounds__(256) void attn_mfma_kernel(
    const u16* __restrict__ Qb, const u16* __restrict__ Kb, const u16* __restrict__ Vt,
    const u16* __restrict__ distT, const float* __restrict__ dens,
    const float* __restrict__ dist_raw, const float* __restrict__ dens_raw,
    u16* __restrict__ O) {
    __shared__ u16 sP[4][512];
    int blk = blockIdx.x;
    int h = blk & 7, kt = (blk >> 3) & 63, b = blk >> 9;
    int t = threadIdx.x, lane = t & 63, w = t >> 6, lq = lane & 15, g = lane >> 4;
    int qrow = kt * 64 + w * 16 + lq;
    const float LOG2E = 1.4426950408889634f;
    float gate = 1.0f + tanhf(dens_raw[0]) * dens[b * KGRID + qrow];
    float c1 = log1pf(__expf(dist_raw[0]));
    float gs = gate * ATT_SCALE * LOG2E;
    float gc = gate * c1 * LOG2E;

    short8 qf = *(const short8*)(Qb + (size_t)(b * KGRID + qrow) * DD + h * HDIM + g * 8);
    const u16* kbase = Kb + (size_t)b * SSRC * DD + h * HDIM + g * 8;
    const u16* vbase = Vt + ((size_t)(b * NHEADS + h) * HDIM + lq) * SSRC + g * 8;
    const u16* dbase = distT + ((size_t)(b * KGRID) + qrow) * SSRC;

    f32x4 acc0 = {0.f, 0.f, 0.f, 0.f}, acc1 = {0.f, 0.f, 0.f, 0.f};
    f32x4 zero = {0.f, 0.f, 0.f, 0.f};
    float lsum = 0.0f;
    u16* myP = sP[w];

    for (int s0 = 0; s0 < SSRC; s0 += 32) {
        #pragma unroll
        for (int tl = 0; tl < 2; tl++) {
            int sb = s0 + tl * 16;
            short8 kf = *(const short8*)(kbase + (size_t)(sb + lq) * DD);
            f32x4 c = __builtin_amdgcn_mfma_f32_16x16x32_bf16(kf, qf, zero, 0, 0, 0);
            uint2 dh = *(const uint2*)(dbase + sb + 4 * g);
            float p0 = exp2f(gs * c[0] - gc * h2f(dh.x));
            float p1 = exp2f(gs * c[1] - gc * h2f(dh.x >> 16));
            float p2 = exp2f(gs * c[2] - gc * h2f(dh.y));
            float p3 = exp2f(gs * c[3] - gc * h2f(dh.y >> 16));
            lsum += (p0 + p1) + (p2 + p3);
            int idx = lq * 32 + tl * 16 + 4 * g;
            *(unsigned int*)&myP[idx]     = cvtpk_bf16(p0, p1);
            *(unsigned int*)&myP[idx + 2] = cvtpk_bf16(p2, p3);
        }
        short8 pf = *(const short8*)&myP[lq * 32 + g * 8];
        short8 v0 = *(const short8*)(vbase + s0);
        short8 v1 = *(const short8*)(vbase + 16 * SSRC + s0);
        acc0 = __builtin_amdgcn_mfma_f32_16x16x32_bf16(v0, pf, acc0, 0, 0, 0);
        acc1 = __builtin_amdgcn_mfma_f32_16x16x32_bf16(v1, pf, acc1, 0, 0, 0);
    }

    lsum += __shfl_xor(lsum, 16, 64);
    lsum += __shfl_xor(lsum, 32, 64);
    float inv = 1.0f / lsum;
    u16* op = O + (size_t)(b * KGRID + qrow) * DD + h * HDIM + 4 * g;
    uint2 o0, o1;
    o0.x = cvtpk_bf16(acc0[0] * inv, acc0[1] * inv);
    o0.y = cvtpk_bf16(acc0[2] * inv, acc0[3] * inv);
    o1.x = cvtpk_bf16(acc1[0] * inv, acc1[1] * inv);
    o1.y = cvtpk_bf16(acc1[2] * inv, acc1[3] * inv);
    *(uint2*)op = o0;
    *(uint2*)(op + 16) = o1;
}

// ---------------------------------------------------------------------------
__global__ void head_kernel(const float* __restrict__ tf, const float* __restrict__ hW,
                            const float* __restrict__ hb, float* __restrict__ out) {
    int w = threadIdx.x >> 6, lane = threadIdx.x & 63;
    int idx = blockIdx.x * 4 + w;
    float4 x = ((const float4*)tf)[(size_t)idx * 64 + lane];
    float4 ww = ((const float4*)hW)[lane];
    float s = x.x * ww.x + x.y * ww.y + x.z * ww.z + x.w * ww.w;
    #pragma unroll
    for (int o = 1; o < 64; o <<= 1) s += __shfl_xor(s, o, 64);
    if (lane == 0) out[idx] = s + hb[0];
}

// ---------------------------------------------------------------------------
extern "C" void kernel_launch(void* const* d_in, const int* in_sizes, int n_in,
                              void* d_out, int out_size, void* d_ws, size_t ws_size,
                              hipStream_t stream) {
    const float* meas_xy = (const float*)d_in[0];
    const float* meas_v  = (const float*)d_in[1];
    const float* bs_xy   = (const float*)d_in[2];
    const float* city    = (const float*)d_in[3];
    const float* meas_W  = (const float*)d_in[4];
    const float* meas_b  = (const float*)d_in[5];
    const float* pW1     = (const float*)d_in[6];
    const float* pb1     = (const float*)d_in[7];
    const float* pW2     = (const float*)d_in[8];
    const float* pb2     = (const float*)d_in[9];
    const float* bs_W    = (const float*)d_in[10];
    const float* bs_b    = (const float*)d_in[11];
    const float* task_emb= (const float*)d_in[12];
    const float* taskp_W = (const float*)d_in[13];
    const float* taskp_b = (const float*)d_in[14];
    const float* grid_pos= (const float*)d_in[15];
    const float* lnq_g   = (const float*)d_in[16];
    const float* lnq_b   = (const float*)d_in[17];
    const float* lnkv_g  = (const float*)d_in[18];
    const float* lnkv_b  = (const float*)d_in[19];
    const float* qW      = (const float*)d_in[20];
    const float* qb      = (const float*)d_in[21];
    const float* kW      = (const float*)d_in[22];
    const float* kb      = (const float*)d_in[23];
    const float* vW      = (const float*)d_in[24];
    const float* vb      = (const float*)d_in[25];
    const float* oW      = (const float*)d_in[26];
    const float* ob      = (const float*)d_in[27];
    const float* dist_raw= (const float*)d_in[28];
    const float* dens_raw= (const float*)d_in[29];
    const float* lnf_g   = (const float*)d_in[30];
    const float* lnf_b   = (const float*)d_in[31];
    const float* f1W     = (const float*)d_in[32];
    const float* f1b     = (const float*)d_in[33];
    const float* f2W     = (const float*)d_in[34];
    const float* f2b     = (const float*)d_in[35];
    const float* tfp_W   = (const float*)d_in[36];
    const float* tfp_b   = (const float*)d_in[37];
    const float* head_W  = (const float*)d_in[38];
    const float* head_b  = (const float*)d_in[39];
    const int*   task_id = (const int*)d_in[40];

    float* ws = (float*)d_ws;
    float* src   = ws;                       // 524288
    float* gridb = src + 524288;             // 4194304
    float* tmp1  = gridb + 4194304;          // 4194304 (fp32 out of task gemm; distT aliases)
    float* sxyb  = tmp1 + 4194304;           // 4096
    float* densb = sxyb + 4096;              // 16384
    float* tvec  = densb + 16384;            // 1024

    // distT aliases tmp1: 8.4M u16 == 4.2M floats exactly. tmp1 is only written
    // by the final task gemm (after last attn use of distT) and read by head.
    u16* distT = (u16*)tmp1;

    u16* wtq  = (u16*)(tvec + 1024);         // 131072 (2 layers)
    u16* wtk  = wtq  + 131072;
    u16* wtv  = wtk  + 131072;
    u16* wto  = wtv  + 131072;
    u16* wtf1 = wto  + 131072;               // 262144
    u16* wtf2 = wtf1 + 262144;               // 262144
    u16* wtt  = wtf2 + 262144;               // 262144
    u16* kvbf = wtt  + 262144;               // 524288
    u16* lnbf = kvbf + 524288;               // 4194304
    u16* qbf  = lnbf + 4194304;              // 4194304
    u16* kbf  = qbf  + 4194304;              // 524288
    u16* vbf  = kbf  + 524288;               // 524288
    u16* vtbf = vbf  + 524288;               // 524288
    u16* obf  = vtbf + 524288;               // 4194304
    u16* fhbf = obf  + 4194304;              // 8388608

    const dim3 B32x8(32, 8);

    task_vec_kernel<<<BB, 256, 0, stream>>>(task_emb, taskp_W, taskp_b, task_id, tvec);
    grid_init_kernel<<<4096, 256, 0, stream>>>(grid_pos, tvec, gridb);
    src_build_kernel<<<BB * SSRC, 256, 0, stream>>>(meas_xy, meas_v, bs_xy, city,
                                                    meas_W, meas_b, pW1, pb1, pW2, pb2,
                                                    bs_W, bs_b, src, sxyb);
    density_kernel<<<4096, 256, 0, stream>>>(meas_xy, densb);
    dist_kernel<<<BB * KGRID, 256, 0, stream>>>(sxyb, distT);

    wconv_kernel<<<dim3(8, 8, 2), B32x8, 0, stream>>>(qW, wtq, 256, 256);
    wconv_kernel<<<dim3(8, 8, 2), B32x8, 0, stream>>>(kW, wtk, 256, 256);
    wconv_kernel<<<dim3(8, 8, 2), B32x8, 0, stream>>>(vW, wtv, 256, 256);
    wconv_kernel<<<dim3(8, 8, 2), B32x8, 0, stream>>>(oW, wto, 256, 256);
    wconv_kernel<<<dim3(16, 8, 2), B32x8, 0, stream>>>(f1W, wtf1, 256, 512);
    wconv_kernel<<<dim3(8, 16, 2), B32x8, 0, stream>>>(f2W, wtf2, 512, 256);
    wconv_kernel<<<dim3(8, 8, 4), B32x8, 0, stream>>>(tfp_W, wtt, 256, 256);

    for (int i = 0; i < NLAYERS; i++) {
        const int w16 = i * 65536, bso = i * DD;
        ln_kernel<<<512, 256, 0, stream>>>(src, lnkv_g + bso, lnkv_b + bso, kvbf, 2048);
        gemm_mfma<0, 0, 1, 0, 0, 256><<<dim3(32, 2), 256, 0, stream>>>(
            kvbf, wtk + w16, kb + bso, tmp1, kbf, 2048, 256, nullptr, 0, 0);
        gemm_mfma<0, 0, 1, 0, 0, 256><<<dim3(32, 2), 256, 0, stream>>>(
            kvbf, wtv + w16, vb + bso, tmp1, vbf, 2048, 256, nullptr, 0, 0);
        vtrans_kernel<<<dim3(8, 16, 4), B32x8, 0, stream>>>(vbf, vtbf);
        ln_kernel<<<4096, 256, 0, stream>>>(gridb, lnq_g + bso, lnq_b + bso, lnbf, 16384);
        gemm_mfma<0, 0, 1, 0, 0, 256><<<dim3(256, 2), 256, 0, stream>>>(
            lnbf, wtq + w16, qb + bso, tmp1, qbf, 16384, 256, nullptr, 0, 0);
        attn_mfma_kernel<<<2048, 256, 0, stream>>>(
            qbf, kbf, vtbf, distT, densb, dist_raw + i, dens_raw + i, obf);
        gemm_mfma<0, 1, 0, 1, 0, 256><<<dim3(256, 2), 256, 0, stream>>>(
            obf, wto + w16, ob + bso, gridb, obf, 16384, 256, nullptr, 0, 0);
        ln_kernel<<<4096, 256, 0, stream>>>(gridb, lnf_g + bso, lnf_b + bso, lnbf, 16384);
        gemm_mfma<1, 0, 1, 0, 0, 256><<<dim3(256, 4), 256, 0, stream>>>(
            lnbf, wtf1 + i * 131072, f1b + i * 512, tmp1, fhbf, 16384, 512, nullptr, 0, 0);
        gemm_mfma<0, 1, 1, 1, 0, 512><<<dim3(256, 2), 256, 0, stream>>>(
            fhbf, wtf2 + i * 131072, f2b + bso, gridb, lnbf, 16384, 256, nullptr, 0, 0);
    }

    // NOTE: task gemm writes tmp1 (OF32) — this clobbers distT, which is safe
    // because all attn uses of distT are complete by this point.
    gemm_mfma<1, 0, 0, 1, 1, 256><<<dim3(256, 2), 256, 0, stream>>>(
        lnbf, wtt, tfp_b, tmp1, obf, 16384, 256, task_id, 65536, 256);
    head_kernel<<<4096, 256, 0, stream>>>(tmp1, head_W, head_b, (float*)d_out);
}

// Round 7
// 584.831 us; speedup vs baseline: 1.3796x; 1.3796x over previous
//
#include <hip/hip_runtime.h>
#include <hip/hip_fp16.h>
#include <math.h>

#define DD 256
#define NHEADS 8
#define HDIM 32
#define NLAYERS 2
#define GSZ 64
#define KGRID 4096      // GS*GS
#define TTASK 4
#define BB 4
#define NMEAS 511
#define SSRC 512        // N+1
#define HCITY 128
#define WCITY 128
#define ATT_SCALE 0.17677669529663687f   // 32^-0.5
#define INV2S2 78.125f                   // 1/(2*0.08^2)

typedef unsigned short u16;
typedef __attribute__((ext_vector_type(8))) short short8;
typedef __attribute__((ext_vector_type(4))) float f32x4;

__device__ __forceinline__ u16 f2bf(float f) {
    union { float f; unsigned int u; } x; x.f = f;
    return (u16)((x.u + 0x7fffu + ((x.u >> 16) & 1u)) >> 16);
}
// HW packed f32->bf16 RNE (1 instr for 2 values)  [T12 recipe]
__device__ __forceinline__ unsigned int cvtpk_bf16(float a, float b) {
    unsigned int r;
    asm("v_cvt_pk_bf16_f32 %0, %1, %2" : "=v"(r) : "v"(a), "v"(b));
    return r;
}
// f16 (low 16 bits of u) -> f32
__device__ __forceinline__ float h2f(unsigned int u) {
    float r;
    asm("v_cvt_f32_f16 %0, %1" : "=v"(r) : "v"(u));
    return r;
}
__device__ __forceinline__ float gelu_f(float x) {
    return 0.5f * x * (1.0f + erff(x * 0.7071067811865476f));
}

// ---------------------------------------------------------------------------
__global__ void task_vec_kernel(const float* __restrict__ task_emb,
                                const float* __restrict__ tpW,
                                const float* __restrict__ tpb,
                                const int* __restrict__ task_id,
                                float* __restrict__ tv) {
    int b = blockIdx.x, t = threadIdx.x;
    int id = task_id[b];
    float a = tpb[t];
    for (int e = 0; e < DD; e++) a = fmaf(task_emb[id * DD + e], tpW[e * DD + t], a);
    tv[b * DD + t] = a;
}

__global__ void grid_init_kernel(const float* __restrict__ grid_pos,
                                 const float* __restrict__ tv,
                                 float* __restrict__ g) {
    int f = blockIdx.x * 256 + threadIdx.x;
    int b = f >> 18;
    float4 gp = ((const float4*)grid_pos)[f & 262143];
    float4 tvv = ((const float4*)tv)[b * 64 + (f & 63)];
    float4 o; o.x = gp.x + tvv.x; o.y = gp.y + tvv.y; o.z = gp.z + tvv.z; o.w = gp.w + tvv.w;
    ((float4*)g)[f] = o;
}

// ---------------------------------------------------------------------------
__global__ __launch_bounds__(256) void src_build_kernel(
    const float* __restrict__ meas_xy, const float* __restrict__ meas_v,
    const float* __restrict__ bs_xy, const float* __restrict__ city,
    const float* __restrict__ meas_W, const float* __restrict__ meas_b,
    const float* __restrict__ pW1, const float* __restrict__ pb1,
    const float* __restrict__ pW2, const float* __restrict__ pb2,
    const float* __restrict__ bs_W, const float* __restrict__ bs_b,
    float* __restrict__ src, float* __restrict__ src_xy) {
    __shared__ float sp[81];
    __shared__ float sh[DD];
    int b = blockIdx.x / SSRC, s = blockIdx.x % SSRC, t = threadIdx.x;
    if (s < NMEAS) {
        float mx = meas_xy[(b * NMEAS + s) * 2];
        float my = meas_xy[(b * NMEAS + s) * 2 + 1];
        float mv = meas_v[b * NMEAS + s];
        int cx = (int)rintf(mx * 127.0f); cx = min(max(cx, 0), 127);
        int cy = (int)rintf(my * 127.0f); cy = min(max(cy, 0), 127);
        if (t < 81) {
            int rr = cy + t / 9 - 4, cc = cx + t % 9 - 4;
            sp[t] = (rr >= 0 && rr < HCITY && cc >= 0 && cc < WCITY)
                        ? city[(b * HCITY + rr) * WCITY + cc] : 0.0f;
        }
        __syncthreads();
        float a1 = pb1[t];
        #pragma unroll 9
        for (int e = 0; e < 81; e++) a1 = fmaf(sp[e], pW1[e * DD + t], a1);
        sh[t] = gelu_f(a1);
        __syncthreads();
        float a2 = pb2[t];
        for (int e = 0; e < DD; e++) a2 = fmaf(sh[e], pW2[e * DD + t], a2);
        float mt = mx * meas_W[t] + my * meas_W[DD + t] + mv * meas_W[2 * DD + t] + meas_b[t];
        src[((size_t)(b * SSRC + s)) * DD + t] = mt + a2;
        if (t == 0) { src_xy[(b * SSRC + s) * 2] = mx; src_xy[(b * SSRC + s) * 2 + 1] = my; }
    } else {
        float bx = bs_xy[b * 2], by = bs_xy[b * 2 + 1];
        src[((size_t)(b * SSRC + s)) * DD + t] = bx * bs_W[t] + by * bs_W[DD + t] + bs_b[t];
        if (t == 0) { src_xy[(b * SSRC + s) * 2] = bx; src_xy[(b * SSRC + s) * 2 + 1] = by; }
    }
}

// ---------------------------------------------------------------------------
__global__ void density_kernel(const float* __restrict__ meas_xy, float* __restrict__ dens) {
    int w = threadIdx.x >> 6, lane = threadIdx.x & 63;
    int idx = blockIdx.x * 4 + w;
    int b = idx >> 12, k = idx & 4095;
    float gx = ((k & 63) + 0.5f) * (1.0f / 64.0f);
    float gy = ((k >> 6) + 0.5f) * (1.0f / 64.0f);
    float s = 0.0f;
    for (int n = lane; n < NMEAS; n += 64) {
        float2 xy = ((const float2*)meas_xy)[b * NMEAS + n];
        float dx = gx - xy.x, dy = gy - xy.y;
        s += __expf(-(dx * dx + dy * dy) * INV2S2);
    }
    #pragma unroll
    for (int o = 1; o < 64; o <<= 1) s += __shfl_xor(s, o, 64);
    if (lane == 0) dens[idx] = s * (1.0f / 511.0f);
}

// ---------------------------------------------------------------------------
// dist table: dt[b][k][s] = |gxy_k - src_xy[b][s]| as fp16 (RNE). 16.7 MB.
__global__ __launch_bounds__(256) void dist_kernel(const float* __restrict__ sxy_g,
                                                   u16* __restrict__ dt) {
    __shared__ float2 sxy[SSRC];
    int bk = blockIdx.x;             // b*4096 + k
    int b = bk >> 12, k = bk & 4095;
    int t = threadIdx.x;
    sxy[t]       = ((const float2*)sxy_g)[b * SSRC + t];
    sxy[t + 256] = ((const float2*)sxy_g)[b * SSRC + t + 256];
    __syncthreads();
    float gx = ((k & 63) + 0.5f) * (1.0f / 64.0f);
    float gy = ((k >> 6) + 0.5f) * (1.0f / 64.0f);
    float2 p0 = sxy[2 * t], p1 = sxy[2 * t + 1];
    float dx0 = gx - p0.x, dy0 = gy - p0.y;
    float dx1 = gx - p1.x, dy1 = gy - p1.y;
    float d0 = sqrtf(dx0 * dx0 + dy0 * dy0);
    float d1 = sqrtf(dx1 * dx1 + dy1 * dy1);
    __half h0 = __float2half(d0), h1 = __float2half(d1);   // RNE
    unsigned int pk = (unsigned int)__half_as_ushort(h0) |
                      ((unsigned int)__half_as_ushort(h1) << 16);
    ((unsigned int*)dt)[(size_t)bk * 256 + t] = pk;
}

// ---------------------------------------------------------------------------
// LayerNorm: one wave per row of 256; bf16 output.
__global__ void ln_kernel(const float* __restrict__ X, const float* __restrict__ g,
                          const float* __restrict__ bvec, u16* __restrict__ Yb, int rows) {
    int w = threadIdx.x >> 6, lane = threadIdx.x & 63;
    int row = blockIdx.x * 4 + w;
    if (row >= rows) return;
    float4 x = ((const float4*)X)[(size_t)row * 64 + lane];
    float s = x.x + x.y + x.z + x.w;
    float q = x.x * x.x + x.y * x.y + x.z * x.z + x.w * x.w;
    #pragma unroll
    for (int o = 1; o < 64; o <<= 1) { s += __shfl_xor(s, o, 64); q += __shfl_xor(q, o, 64); }
    float m = s * (1.0f / 256.0f);
    float v = q * (1.0f / 256.0f) - m * m;
    float rs = rsqrtf(v + 1e-5f);
    float4 gg = ((const float4*)g)[lane], bb = ((const float4*)bvec)[lane];
    float4 y;
    y.x = (x.x - m) * rs * gg.x + bb.x;
    y.y = (x.y - m) * rs * gg.y + bb.y;
    y.z = (x.z - m) * rs * gg.z + bb.z;
    y.w = (x.w - m) * rs * gg.w + bb.w;
    uint2 o2;
    o2.x = cvtpk_bf16(y.x, y.y);
    o2.y = cvtpk_bf16(y.z, y.w);
    *(uint2*)&Yb[(size_t)row * 256 + lane * 4] = o2;
}

// ---------------------------------------------------------------------------
// Weight convert: W[z][Kd][Nd] fp32 -> Wt[z][Nd][Kd] bf16 (32x32 LDS tiles).
__global__ __launch_bounds__(256) void wconv_kernel(const float* __restrict__ W,
                                                    u16* __restrict__ Wt, int Kd, int Nd) {
    __shared__ float L[32][33];
    int z = blockIdx.z;
    size_t zoff = (size_t)z * Kd * Nd;
    int n0 = blockIdx.x * 32, k0 = blockIdx.y * 32;
    int tx = threadIdx.x, ty = threadIdx.y;
    #pragma unroll
    for (int yy = 0; yy < 4; yy++)
        L[tx][ty + 8 * yy] = W[zoff + (size_t)(k0 + ty + 8 * yy) * Nd + n0 + tx];
    __syncthreads();
    #pragma unroll
    for (int yy = 0; yy < 4; yy++)
        Wt[zoff + (size_t)(n0 + ty + 8 * yy) * Kd + k0 + tx] = f2bf(L[ty + 8 * yy][tx]);
}

// V transpose: V[b*512+s][256] bf16 -> Vt[(b*256+n)][512] bf16.
__global__ __launch_bounds__(256) void vtrans_kernel(const u16* __restrict__ V,
                                                     u16* __restrict__ Vt) {
    __shared__ u16 L[32][33];
    int b = blockIdx.z;
    int n0 = blockIdx.x * 32, s0 = blockIdx.y * 32;
    int tx = threadIdx.x, ty = threadIdx.y;
    #pragma unroll
    for (int yy = 0; yy < 4; yy++)
        L[tx][ty + 8 * yy] = V[(size_t)(b * SSRC + s0 + ty + 8 * yy) * DD + n0 + tx];
    __syncthreads();
    #pragma unroll
    for (int yy = 0; yy < 4; yy++)
        Vt[(size_t)(b * DD + n0 + ty + 8 * yy) * SSRC + s0 + tx] = L[ty + 8 * yy][tx];
}

// ---------------------------------------------------------------------------
// LDS-tiled bf16 MFMA GEMM: C = [res +] act(A @ Wt^T + bias).
// A[M][KD] bf16, Wt[N][KD] bf16. Tile BM=128 x BN=64, BK=64, 256 thr = 4 waves.
// Wave w -> 32 m-rows (2 frag-rows) x 64 n-cols (4 frag-cols). Double-buffered
// LDS, reg-staged, XOR-swizzled 16B granules -> 2-way (free) frag reads.
template <int ACT, int RES, int OBF, int OF32, int BATW, int KD>
__global__ __launch_bounds__(256) void gemm_lds(
    const u16* __restrict__ A, const u16* __restrict__ Wt,
    const float* __restrict__ bias, float* __restrict__ C, u16* __restrict__ Cb,
    int Nfull, const int* __restrict__ task_id, int wstride, int bstride) {
    __shared__ u16 sA[2][128][64];
    __shared__ u16 sB[2][64][64];
    int t = threadIdx.x;
    int w = t >> 6, lane = t & 63, lq = lane & 15, g = lane >> 4;
    int m0 = blockIdx.x * 128, n0 = blockIdx.y * 64;
    const u16* Wp = Wt;
    const float* bp = bias;
    if (BATW) {
        int id = task_id[m0 / KGRID];
        Wp += (size_t)id * wstride;
        bp += (size_t)id * bstride;
    }
    // staging assignment: A row ar (2 thr/row, 4 granules each), B row br (4 thr/row, 2 granules)
    int ar = t >> 1, ah = (t & 1) * 4;
    int br = t >> 2, bq = (t & 3) * 2;
    const u16* Ag = A + (size_t)(m0 + ar) * KD + ah * 8;
    const u16* Bg = Wp + (size_t)(n0 + br) * KD + bq * 8;
    uint4 avr[4], bvr[2];
    #pragma unroll
    for (int i = 0; i < 4; i++) avr[i] = *(const uint4*)(Ag + i * 8);
    #pragma unroll
    for (int i = 0; i < 2; i++) bvr[i] = *(const uint4*)(Bg + i * 8);

    f32x4 acc[2][4];
    #pragma unroll
    for (int fm = 0; fm < 2; fm++)
        #pragma unroll
        for (int fn = 0; fn < 4; fn++) acc[fm][fn] = {0.f, 0.f, 0.f, 0.f};

    const int NK = KD / 64;
    #pragma unroll
    for (int ks = 0; ks < NK; ks++) {
        int cur = ks & 1;
        #pragma unroll
        for (int i = 0; i < 4; i++)
            *(uint4*)&sA[cur][ar][((ah + i) ^ (ar & 7)) * 8] = avr[i];
        #pragma unroll
        for (int i = 0; i < 2; i++)
            *(uint4*)&sB[cur][br][((bq + i) ^ (br & 7)) * 8] = bvr[i];
        if (ks + 1 < NK) {
            #pragma unroll
            for (int i = 0; i < 4; i++) avr[i] = *(const uint4*)(Ag + (ks + 1) * 64 + i * 8);
            #pragma unroll
            for (int i = 0; i < 2; i++) bvr[i] = *(const uint4*)(Bg + (ks + 1) * 64 + i * 8);
        }
        __syncthreads();
        #pragma unroll
        for (int sub = 0; sub < 2; sub++) {
            short8 af[2], bf[4];
            #pragma unroll
            for (int fm = 0; fm < 2; fm++)
                af[fm] = *(const short8*)&sA[cur][w * 32 + fm * 16 + lq][((sub * 4 + g) ^ (lq & 7)) * 8];
            #pragma unroll
            for (int fn = 0; fn < 4; fn++)
                bf[fn] = *(const short8*)&sB[cur][fn * 16 + lq][((sub * 4 + g) ^ (lq & 7)) * 8];
            #pragma unroll
            for (int fm = 0; fm < 2; fm++)
                #pragma unroll
                for (int fn = 0; fn < 4; fn++)
                    acc[fm][fn] = __builtin_amdgcn_mfma_f32_16x16x32_bf16(af[fm], bf[fn], acc[fm][fn], 0, 0, 0);
        }
        __syncthreads();
    }
    #pragma unroll
    for (int fm = 0; fm < 2; fm++) {
        int mbase = m0 + w * 32 + fm * 16 + 4 * g;
        #pragma unroll
        for (int fn = 0; fn < 4; fn++) {
            int col = n0 + fn * 16 + lq;
            float bv = bp[col];
            #pragma unroll
            for (int r = 0; r < 4; r++) {
                float o = acc[fm][fn][r] + bv;
                if (ACT) o = gelu_f(o);
                size_t off = (size_t)(mbase + r) * Nfull + col;
                if (RES) o += C[off];
                if (OF32) C[off] = o;
                if (OBF) Cb[off] = f2bf(o);
            }
        }
    }
}

// ---------------------------------------------------------------------------
// MFMA attention v4: block = (b, 32 q-rows) x 8 waves = 8 heads.
// dist slab (32x512 fp16) staged ONCE per block into LDS (coalesced), shared
// by all heads. Wave w = head w, 2 q-chunks of 16. Swapped-operand MFMA.
#define DPAD 520
__global__ __launch_bounds__(512) void attn_mfma_kernel(
    const u16* __restrict__ Qb, const u16* __restrict__ Kb, const u16* __restrict__ Vt,
    const u16* __restrict__ distT, const float* __restrict__ dens,
    const float* __restrict__ dist_raw, const float* __restrict__ dens_raw,
    u16* __restrict__ O) {
    __shared__ u16 sD[32][DPAD];
    __shared__ u16 sP[16][512];          // [wave*2+chunk][16q x 32s]
    int blk = blockIdx.x;                // b*128 + kt
    int kt = blk & 127, b = blk >> 7;
    int t = threadIdx.x;
    {   // stage dist rows kt*32..kt*32+31 (coalesced 64B/thread)
        int r = t >> 4, cs = (t & 15) * 32;
        const u16* gp = distT + ((size_t)(b * KGRID) + kt * 32 + r) * SSRC + cs;
        uint4 d0 = *(const uint4*)gp;
        uint4 d1 = *(const uint4*)(gp + 8);
        uint4 d2 = *(const uint4*)(gp + 16);
        uint4 d3 = *(const uint4*)(gp + 24);
        *(uint4*)&sD[r][cs] = d0;
        *(uint4*)&sD[r][cs + 8] = d1;
        *(uint4*)&sD[r][cs + 16] = d2;
        *(uint4*)&sD[r][cs + 24] = d3;
    }
    __syncthreads();

    int w = t >> 6, lane = t & 63, lq = lane & 15, g = lane >> 4;
    int h = w;
    const float LOG2E = 1.4426950408889634f;
    float th = tanhf(dens_raw[0]);
    float c1 = log1pf(__expf(dist_raw[0]));
    float gs[2], gc[2];
    short8 qf[2];
    #pragma unroll
    for (int qc = 0; qc < 2; qc++) {
        int qrow = kt * 32 + qc * 16 + lq;
        float gate = 1.0f + th * dens[b * KGRID + qrow];
        gs[qc] = gate * ATT_SCALE * LOG2E;
        gc[qc] = gate * c1 * LOG2E;
        qf[qc] = *(const short8*)(Qb + (size_t)(b * KGRID + qrow) * DD + h * HDIM + g * 8);
    }
    const u16* kbase = Kb + (size_t)b * SSRC * DD + h * HDIM + g * 8;
    const u16* vbase = Vt + ((size_t)(b * NHEADS + h) * HDIM + lq) * SSRC + g * 8;

    f32x4 accA[2] = {{0.f, 0.f, 0.f, 0.f}, {0.f, 0.f, 0.f, 0.f}};
    f32x4 accB[2] = {{0.f, 0.f, 0.f, 0.f}, {0.f, 0.f, 0.f, 0.f}};
    f32x4 zero = {0.f, 0.f, 0.f, 0.f};
    float lsum[2] = {0.f, 0.f};

    for (int s0 = 0; s0 < SSRC; s0 += 32) {
        #pragma unroll
        for (int tl = 0; tl < 2; tl++) {
            int sb = s0 + tl * 16;
            short8 kf = *(const short8*)(kbase + (size_t)(sb + lq) * DD);
            #pragma unroll
            for (int qc = 0; qc < 2; qc++) {
                f32x4 c = __builtin_amdgcn_mfma_f32_16x16x32_bf16(kf, qf[qc], zero, 0, 0, 0);
                uint2 dh = *(const uint2*)&sD[qc * 16 + lq][sb + 4 * g];
                float p0 = exp2f(gs[qc] * c[0] - gc[qc] * h2f(dh.x));
                float p1 = exp2f(gs[qc] * c[1] - gc[qc] * h2f(dh.x >> 16));
                float p2 = exp2f(gs[qc] * c[2] - gc[qc] * h2f(dh.y));
                float p3 = exp2f(gs[qc] * c[3] - gc[qc] * h2f(dh.y >> 16));
                lsum[qc] += (p0 + p1) + (p2 + p3);
                int idx = lq * 32 + tl * 16 + 4 * g;
                *(unsigned int*)&sP[w * 2 + qc][idx]     = cvtpk_bf16(p0, p1);
                *(unsigned int*)&sP[w * 2 + qc][idx + 2] = cvtpk_bf16(p2, p3);
            }
        }
        short8 v0 = *(const short8*)(vbase + s0);
        short8 v1 = *(const short8*)(vbase + 16 * SSRC + s0);
        #pragma unroll
        for (int qc = 0; qc < 2; qc++) {
            short8 pf = *(const short8*)&sP[w * 2 + qc][lq * 32 + g * 8];
            accA[qc] = __builtin_amdgcn_mfma_f32_16x16x32_bf16(v0, pf, accA[qc], 0, 0, 0);
            accB[qc] = __builtin_amdgcn_mfma_f32_16x16x32_bf16(v1, pf, accB[qc], 0, 0, 0);
        }
    }

    #pragma unroll
    for (int qc = 0; qc < 2; qc++) {
        float ls = lsum[qc];
        ls += __shfl_xor(ls, 16, 64);
        ls += __shfl_xor(ls, 32, 64);
        float inv = 1.0f / ls;
        int qrow = kt * 32 + qc * 16 + lq;
        u16* op = O + (size_t)(b * KGRID + qrow) * DD + h * HDIM + 4 * g;
        uint2 o0, o1;
        o0.x = cvtpk_bf16(accA[qc][0] * inv, accA[qc][1] * inv);
        o0.y = cvtpk_bf16(accA[qc][2] * inv, accA[qc][3] * inv);
        o1.x = cvtpk_bf16(accB[qc][0] * inv, accB[qc][1] * inv);
        o1.y = cvtpk_bf16(accB[qc][2] * inv, accB[qc][3] * inv);
        *(uint2*)op = o0;
        *(uint2*)(op + 16) = o1;
    }
}

// ---------------------------------------------------------------------------
__global__ void head_kernel(const float* __restrict__ tf, const float* __restrict__ hW,
                            const float* __restrict__ hb, float* __restrict__ out) {
    int w = threadIdx.x >> 6, lane = threadIdx.x & 63;
    int idx = blockIdx.x * 4 + w;
    float4 x = ((const float4*)tf)[(size_t)idx * 64 + lane];
    float4 ww = ((const float4*)hW)[lane];
    float s = x.x * ww.x + x.y * ww.y + x.z * ww.z + x.w * ww.w;
    #pragma unroll
    for (int o = 1; o < 64; o <<= 1) s += __shfl_xor(s, o, 64);
    if (lane == 0) out[idx] = s + hb[0];
}

// ---------------------------------------------------------------------------
extern "C" void kernel_launch(void* const* d_in, const int* in_sizes, int n_in,
                              void* d_out, int out_size, void* d_ws, size_t ws_size,
                              hipStream_t stream) {
    const float* meas_xy = (const float*)d_in[0];
    const float* meas_v  = (const float*)d_in[1];
    const float* bs_xy   = (const float*)d_in[2];
    const float* city    = (const float*)d_in[3];
    const float* meas_W  = (const float*)d_in[4];
    const float* meas_b  = (const float*)d_in[5];
    const float* pW1     = (const float*)d_in[6];
    const float* pb1     = (const float*)d_in[7];
    const float* pW2     = (const float*)d_in[8];
    const float* pb2     = (const float*)d_in[9];
    const float* bs_W    = (const float*)d_in[10];
    const float* bs_b    = (const float*)d_in[11];
    const float* task_emb= (const float*)d_in[12];
    const float* taskp_W = (const float*)d_in[13];
    const float* taskp_b = (const float*)d_in[14];
    const float* grid_pos= (const float*)d_in[15];
    const float* lnq_g   = (const float*)d_in[16];
    const float* lnq_b   = (const float*)d_in[17];
    const float* lnkv_g  = (const float*)d_in[18];
    const float* lnkv_b  = (const float*)d_in[19];
    const float* qW      = (const float*)d_in[20];
    const float* qb      = (const float*)d_in[21];
    const float* kW      = (const float*)d_in[22];
    const float* kb      = (const float*)d_in[23];
    const float* vW      = (const float*)d_in[24];
    const float* vb      = (const float*)d_in[25];
    const float* oW      = (const float*)d_in[26];
    const float* ob      = (const float*)d_in[27];
    const float* dist_raw= (const float*)d_in[28];
    const float* dens_raw= (const float*)d_in[29];
    const float* lnf_g   = (const float*)d_in[30];
    const float* lnf_b   = (const float*)d_in[31];
    const float* f1W     = (const float*)d_in[32];
    const float* f1b     = (const float*)d_in[33];
    const float* f2W     = (const float*)d_in[34];
    const float* f2b     = (const float*)d_in[35];
    const float* tfp_W   = (const float*)d_in[36];
    const float* tfp_b   = (const float*)d_in[37];
    const float* head_W  = (const float*)d_in[38];
    const float* head_b  = (const float*)d_in[39];
    const int*   task_id = (const int*)d_in[40];

    float* ws = (float*)d_ws;
    float* src   = ws;                       // 524288
    float* gridb = src + 524288;             // 4194304
    float* tmp1  = gridb + 4194304;          // 4194304 (task-gemm fp32 out; distT aliases)
    float* sxyb  = tmp1 + 4194304;           // 4096
    float* densb = sxyb + 4096;              // 16384
    float* tvec  = densb + 16384;            // 1024

    // distT aliases tmp1 (8.4M u16 == 4.2M floats). tmp1 is written only by the
    // final task gemm, after the last attn read of distT.
    u16* distT = (u16*)tmp1;

    u16* wtq  = (u16*)(tvec + 1024);         // 131072 (2 layers)
    u16* wtk  = wtq  + 131072;
    u16* wtv  = wtk  + 131072;
    u16* wto  = wtv  + 131072;
    u16* wtf1 = wto  + 131072;               // 262144
    u16* wtf2 = wtf1 + 262144;               // 262144
    u16* wtt  = wtf2 + 262144;               // 262144
    u16* kvbf = wtt  + 262144;               // 524288
    u16* lnbf = kvbf + 524288;               // 4194304
    u16* qbf  = lnbf + 4194304;              // 4194304
    u16* kbf  = qbf  + 4194304;              // 524288
    u16* vbf  = kbf  + 524288;               // 524288
    u16* vtbf = vbf  + 524288;               // 524288
    u16* obf  = vtbf + 524288;               // 4194304
    u16* fhbf = obf  + 4194304;              // 8388608

    const dim3 B32x8(32, 8);

    task_vec_kernel<<<BB, 256, 0, stream>>>(task_emb, taskp_W, taskp_b, task_id, tvec);
    grid_init_kernel<<<4096, 256, 0, stream>>>(grid_pos, tvec, gridb);
    src_build_kernel<<<BB * SSRC, 256, 0, stream>>>(meas_xy, meas_v, bs_xy, city,
                                                    meas_W, meas_b, pW1, pb1, pW2, pb2,
                                                    bs_W, bs_b, src, sxyb);
    density_kernel<<<4096, 256, 0, stream>>>(meas_xy, densb);
    dist_kernel<<<BB * KGRID, 256, 0, stream>>>(sxyb, distT);

    wconv_kernel<<<dim3(8, 8, 2), B32x8, 0, stream>>>(qW, wtq, 256, 256);
    wconv_kernel<<<dim3(8, 8, 2), B32x8, 0, stream>>>(kW, wtk, 256, 256);
    wconv_kernel<<<dim3(8, 8, 2), B32x8, 0, stream>>>(vW, wtv, 256, 256);
    wconv_kernel<<<dim3(8, 8, 2), B32x8, 0, stream>>>(oW, wto, 256, 256);
    wconv_kernel<<<dim3(16, 8, 2), B32x8, 0, stream>>>(f1W, wtf1, 256, 512);
    wconv_kernel<<<dim3(8, 16, 2), B32x8, 0, stream>>>(f2W, wtf2, 512, 256);
    wconv_kernel<<<dim3(8, 8, 4), B32x8, 0, stream>>>(tfp_W, wtt, 256, 256);

    for (int i = 0; i < NLAYERS; i++) {
        const int w16 = i * 65536, bso = i * DD;
        ln_kernel<<<512, 256, 0, stream>>>(src, lnkv_g + bso, lnkv_b + bso, kvbf, 2048);
        gemm_lds<0, 0, 1, 0, 0, 256><<<dim3(16, 4), 256, 0, stream>>>(
            kvbf, wtk + w16, kb + bso, tmp1, kbf, 256, nullptr, 0, 0);
        gemm_lds<0, 0, 1, 0, 0, 256><<<dim3(16, 4), 256, 0, stream>>>(
            kvbf, wtv + w16, vb + bso, tmp1, vbf, 256, nullptr, 0, 0);
        vtrans_kernel<<<dim3(8, 16, 4), B32x8, 0, stream>>>(vbf, vtbf);
        ln_kernel<<<4096, 256, 0, stream>>>(gridb, lnq_g + bso, lnq_b + bso, lnbf, 16384);
        gemm_lds<0, 0, 1, 0, 0, 256><<<dim3(128, 4), 256, 0, stream>>>(
            lnbf, wtq + w16, qb + bso, tmp1, qbf, 256, nullptr, 0, 0);
        attn_mfma_kernel<<<BB * (KGRID / 32), 512, 0, stream>>>(
            qbf, kbf, vtbf, distT, densb, dist_raw + i, dens_raw + i, obf);
        gemm_lds<0, 1, 0, 1, 0, 256><<<dim3(128, 4), 256, 0, stream>>>(
            obf, wto + w16, ob + bso, gridb, obf, 256, nullptr, 0, 0);
        ln_kernel<<<4096, 256, 0, stream>>>(gridb, lnf_g + bso, lnf_b + bso, lnbf, 16384);
        gemm_lds<1, 0, 1, 0, 0, 256><<<dim3(128, 8), 256, 0, stream>>>(
            lnbf, wtf1 + i * 131072, f1b + i * 512, tmp1, fhbf, 512, nullptr, 0, 0);
        gemm_lds<0, 1, 1, 1, 0, 512><<<dim3(128, 4), 256, 0, stream>>>(
            fhbf, wtf2 + i * 131072, f2b + bso, gridb, lnbf, 256, nullptr, 0, 0);
    }

    // task gemm writes tmp1 (OF32) — clobbers distT, safe: all attn reads done.
    gemm_lds<1, 0, 0, 1, 1, 256><<<dim3(128, 4), 256, 0, stream>>>(
        lnbf, wtt, tfp_b, tmp1, obf, 256, task_id, 65536, 256);
    head_kernel<<<4096, 256, 0, stream>>>(tmp1, head_W, head_b, (float*)d_out);
}

// Round 8
// 517.373 us; speedup vs baseline: 1.5595x; 1.1304x over previous
//
#include <hip/hip_runtime.h>
#include <hip/hip_fp16.h>
#include <math.h>

#define DD 256
#define NHEADS 8
#define HDIM 32
#define NLAYERS 2
#define GSZ 64
#define KGRID 4096      // GS*GS
#define TTASK 4
#define BB 4
#define NMEAS 511
#define SSRC 512        // N+1
#define HCITY 128
#define WCITY 128
#define ATT_SCALE 0.17677669529663687f   // 32^-0.5
#define INV2S2 78.125f                   // 1/(2*0.08^2)

typedef unsigned short u16;
typedef __attribute__((ext_vector_type(8))) short short8;
typedef __attribute__((ext_vector_type(4))) float f32x4;

__device__ __forceinline__ u16 f2bf(float f) {
    union { float f; unsigned int u; } x; x.f = f;
    return (u16)((x.u + 0x7fffu + ((x.u >> 16) & 1u)) >> 16);
}
// HW packed f32->bf16 RNE (1 instr for 2 values)  [T12 recipe]
__device__ __forceinline__ unsigned int cvtpk_bf16(float a, float b) {
    unsigned int r;
    asm("v_cvt_pk_bf16_f32 %0, %1, %2" : "=v"(r) : "v"(a), "v"(b));
    return r;
}
// f16 (low 16 bits of u) -> f32
__device__ __forceinline__ float h2f(unsigned int u) {
    float r;
    asm("v_cvt_f32_f16 %0, %1" : "=v"(r) : "v"(u));
    return r;
}
__device__ __forceinline__ float gelu_f(float x) {
    return 0.5f * x * (1.0f + erff(x * 0.7071067811865476f));
}
// async global->LDS, 16B per lane; lptr must be the wave-uniform chunk base
// (HW scatters lane i to base + 16*i); gptr is per-lane.
__device__ __forceinline__ void gload16(const u16* g, u16* l) {
    __builtin_amdgcn_global_load_lds(
        (__attribute__((address_space(1))) void*)g,
        (__attribute__((address_space(3))) void*)l, 16, 0, 0);
}

// ---------------------------------------------------------------------------
__global__ void task_vec_kernel(const float* __restrict__ task_emb,
                                const float* __restrict__ tpW,
                                const float* __restrict__ tpb,
                                const int* __restrict__ task_id,
                                float* __restrict__ tv) {
    int b = blockIdx.x, t = threadIdx.x;
    int id = task_id[b];
    float a = tpb[t];
    for (int e = 0; e < DD; e++) a = fmaf(task_emb[id * DD + e], tpW[e * DD + t], a);
    tv[b * DD + t] = a;
}

__global__ void grid_init_kernel(const float* __restrict__ grid_pos,
                                 const float* __restrict__ tv,
                                 float* __restrict__ g) {
    int f = blockIdx.x * 256 + threadIdx.x;
    int b = f >> 18;
    float4 gp = ((const float4*)grid_pos)[f & 262143];
    float4 tvv = ((const float4*)tv)[b * 64 + (f & 63)];
    float4 o; o.x = gp.x + tvv.x; o.y = gp.y + tvv.y; o.z = gp.z + tvv.z; o.w = gp.w + tvv.w;
    ((float4*)g)[f] = o;
}

// ---------------------------------------------------------------------------
__global__ __launch_bounds__(256) void src_build_kernel(
    const float* __restrict__ meas_xy, const float* __restrict__ meas_v,
    const float* __restrict__ bs_xy, const float* __restrict__ city,
    const float* __restrict__ meas_W, const float* __restrict__ meas_b,
    const float* __restrict__ pW1, const float* __restrict__ pb1,
    const float* __restrict__ pW2, const float* __restrict__ pb2,
    const float* __restrict__ bs_W, const float* __restrict__ bs_b,
    float* __restrict__ src, float* __restrict__ src_xy) {
    __shared__ float sp[81];
    __shared__ float sh[DD];
    int b = blockIdx.x / SSRC, s = blockIdx.x % SSRC, t = threadIdx.x;
    if (s < NMEAS) {
        float mx = meas_xy[(b * NMEAS + s) * 2];
        float my = meas_xy[(b * NMEAS + s) * 2 + 1];
        float mv = meas_v[b * NMEAS + s];
        int cx = (int)rintf(mx * 127.0f); cx = min(max(cx, 0), 127);
        int cy = (int)rintf(my * 127.0f); cy = min(max(cy, 0), 127);
        if (t < 81) {
            int rr = cy + t / 9 - 4, cc = cx + t % 9 - 4;
            sp[t] = (rr >= 0 && rr < HCITY && cc >= 0 && cc < WCITY)
                        ? city[(b * HCITY + rr) * WCITY + cc] : 0.0f;
        }
        __syncthreads();
        float a1 = pb1[t];
        #pragma unroll 9
        for (int e = 0; e < 81; e++) a1 = fmaf(sp[e], pW1[e * DD + t], a1);
        sh[t] = gelu_f(a1);
        __syncthreads();
        float a2 = pb2[t];
        for (int e = 0; e < DD; e++) a2 = fmaf(sh[e], pW2[e * DD + t], a2);
        float mt = mx * meas_W[t] + my * meas_W[DD + t] + mv * meas_W[2 * DD + t] + meas_b[t];
        src[((size_t)(b * SSRC + s)) * DD + t] = mt + a2;
        if (t == 0) { src_xy[(b * SSRC + s) * 2] = mx; src_xy[(b * SSRC + s) * 2 + 1] = my; }
    } else {
        float bx = bs_xy[b * 2], by = bs_xy[b * 2 + 1];
        src[((size_t)(b * SSRC + s)) * DD + t] = bx * bs_W[t] + by * bs_W[DD + t] + bs_b[t];
        if (t == 0) { src_xy[(b * SSRC + s) * 2] = bx; src_xy[(b * SSRC + s) * 2 + 1] = by; }
    }
}

// ---------------------------------------------------------------------------
__global__ void density_kernel(const float* __restrict__ meas_xy, float* __restrict__ dens) {
    int w = threadIdx.x >> 6, lane = threadIdx.x & 63;
    int idx = blockIdx.x * 4 + w;
    int b = idx >> 12, k = idx & 4095;
    float gx = ((k & 63) + 0.5f) * (1.0f / 64.0f);
    float gy = ((k >> 6) + 0.5f) * (1.0f / 64.0f);
    float s = 0.0f;
    for (int n = lane; n < NMEAS; n += 64) {
        float2 xy = ((const float2*)meas_xy)[b * NMEAS + n];
        float dx = gx - xy.x, dy = gy - xy.y;
        s += __expf(-(dx * dx + dy * dy) * INV2S2);
    }
    #pragma unroll
    for (int o = 1; o < 64; o <<= 1) s += __shfl_xor(s, o, 64);
    if (lane == 0) dens[idx] = s * (1.0f / 511.0f);
}

// ---------------------------------------------------------------------------
// dist table: dt[b][k][s] = |gxy_k - src_xy[b][s]| as fp16 (RNE). 16.7 MB.
__global__ __launch_bounds__(256) void dist_kernel(const float* __restrict__ sxy_g,
                                                   u16* __restrict__ dt) {
    __shared__ float2 sxy[SSRC];
    int bk = blockIdx.x;             // b*4096 + k
    int b = bk >> 12, k = bk & 4095;
    int t = threadIdx.x;
    sxy[t]       = ((const float2*)sxy_g)[b * SSRC + t];
    sxy[t + 256] = ((const float2*)sxy_g)[b * SSRC + t + 256];
    __syncthreads();
    float gx = ((k & 63) + 0.5f) * (1.0f / 64.0f);
    float gy = ((k >> 6) + 0.5f) * (1.0f / 64.0f);
    float2 p0 = sxy[2 * t], p1 = sxy[2 * t + 1];
    float dx0 = gx - p0.x, dy0 = gy - p0.y;
    float dx1 = gx - p1.x, dy1 = gy - p1.y;
    float d0 = sqrtf(dx0 * dx0 + dy0 * dy0);
    float d1 = sqrtf(dx1 * dx1 + dy1 * dy1);
    __half h0 = __float2half(d0), h1 = __float2half(d1);   // RNE
    unsigned int pk = (unsigned int)__half_as_ushort(h0) |
                      ((unsigned int)__half_as_ushort(h1) << 16);
    ((unsigned int*)dt)[(size_t)bk * 256 + t] = pk;
}

// ---------------------------------------------------------------------------
// LayerNorm: one wave per row of 256; bf16 output.
__global__ void ln_kernel(const float* __restrict__ X, const float* __restrict__ g,
                          const float* __restrict__ bvec, u16* __restrict__ Yb, int rows) {
    int w = threadIdx.x >> 6, lane = threadIdx.x & 63;
    int row = blockIdx.x * 4 + w;
    if (row >= rows) return;
    float4 x = ((const float4*)X)[(size_t)row * 64 + lane];
    float s = x.x + x.y + x.z + x.w;
    float q = x.x * x.x + x.y * x.y + x.z * x.z + x.w * x.w;
    #pragma unroll
    for (int o = 1; o < 64; o <<= 1) { s += __shfl_xor(s, o, 64); q += __shfl_xor(q, o, 64); }
    float m = s * (1.0f / 256.0f);
    float v = q * (1.0f / 256.0f) - m * m;
    float rs = rsqrtf(v + 1e-5f);
    float4 gg = ((const float4*)g)[lane], bb = ((const float4*)bvec)[lane];
    float4 y;
    y.x = (x.x - m) * rs * gg.x + bb.x;
    y.y = (x.y - m) * rs * gg.y + bb.y;
    y.z = (x.z - m) * rs * gg.z + bb.z;
    y.w = (x.w - m) * rs * gg.w + bb.w;
    uint2 o2;
    o2.x = cvtpk_bf16(y.x, y.y);
    o2.y = cvtpk_bf16(y.z, y.w);
    *(uint2*)&Yb[(size_t)row * 256 + lane * 4] = o2;
}

// ---------------------------------------------------------------------------
// Weight convert: W[z][Kd][Nd] fp32 -> Wt[z][Nd][Kd] bf16 (32x32 LDS tiles).
__global__ __launch_bounds__(256) void wconv_kernel(const float* __restrict__ W,
                                                    u16* __restrict__ Wt, int Kd, int Nd) {
    __shared__ float L[32][33];
    int z = blockIdx.z;
    size_t zoff = (size_t)z * Kd * Nd;
    int n0 = blockIdx.x * 32, k0 = blockIdx.y * 32;
    int tx = threadIdx.x, ty = threadIdx.y;
    #pragma unroll
    for (int yy = 0; yy < 4; yy++)
        L[tx][ty + 8 * yy] = W[zoff + (size_t)(k0 + ty + 8 * yy) * Nd + n0 + tx];
    __syncthreads();
    #pragma unroll
    for (int yy = 0; yy < 4; yy++)
        Wt[zoff + (size_t)(n0 + ty + 8 * yy) * Kd + k0 + tx] = f2bf(L[ty + 8 * yy][tx]);
}

// V transpose: V[b*512+s][256] bf16 -> Vt[(b*256+n)][512] bf16.
__global__ __launch_bounds__(256) void vtrans_kernel(const u16* __restrict__ V,
                                                     u16* __restrict__ Vt) {
    __shared__ u16 L[32][33];
    int b = blockIdx.z;
    int n0 = blockIdx.x * 32, s0 = blockIdx.y * 32;
    int tx = threadIdx.x, ty = threadIdx.y;
    #pragma unroll
    for (int yy = 0; yy < 4; yy++)
        L[tx][ty + 8 * yy] = V[(size_t)(b * SSRC + s0 + ty + 8 * yy) * DD + n0 + tx];
    __syncthreads();
    #pragma unroll
    for (int yy = 0; yy < 4; yy++)
        Vt[(size_t)(b * DD + n0 + ty + 8 * yy) * SSRC + s0 + tx] = L[ty + 8 * yy][tx];
}

// ---------------------------------------------------------------------------
// m97-style bf16 MFMA GEMM: C = [res +] act(A @ Wt^T + bias).
// A[M][KD] bf16, Wt[N][KD] bf16. Tile 128x128, BK=32, 256 thr = 4 waves;
// wave = 64x64 out (4x4 frags). global_load_lds(16B) staging into linear LDS,
// double-buffered, 2-phase pipeline (stage ks+1 || compute ks, 1 barrier/step).
template <int ACT, int RES, int OBF, int OF32, int BATW, int KD>
__global__ __launch_bounds__(256) void gemm_glds(
    const u16* __restrict__ A, const u16* __restrict__ Wt,
    const float* __restrict__ bias, float* __restrict__ C, u16* __restrict__ Cb,
    int Nfull, const int* __restrict__ task_id, int wstride, int bstride) {
    __shared__ u16 sA[2][128][32];
    __shared__ u16 sB[2][128][32];
    int t = threadIdx.x;
    int w = t >> 6, lane = t & 63, lq = lane & 15, g = lane >> 4;
    int wr = w >> 1, wc = w & 1;
    int m0 = blockIdx.x * 128, n0 = blockIdx.y * 128;
    const u16* Wp = Wt;
    const float* bp = bias;
    if (BATW) {
        int id = task_id[m0 / KGRID];
        Wp += (size_t)id * wstride;
        bp += (size_t)id * bstride;
    }
    // staging: wave w covers A rows [32w,32w+32) and B rows [32w,32w+32).
    // chunk = 16 rows = 1KB; lane l -> row +(l>>2), 16B at byte (l&3)*16
    // (LDS landing = base + 16*l, exactly linear row-major [16][32]).
    int srow = lane >> 2;
    int scol = (lane & 3) * 8;           // u16 elements
    const u16* Ag0 = A  + (size_t)(m0 + w * 32 + srow) * KD + scol;
    const u16* Ag1 = Ag0 + (size_t)16 * KD;
    const u16* Bg0 = Wp + (size_t)(n0 + w * 32 + srow) * KD + scol;
    const u16* Bg1 = Bg0 + (size_t)16 * KD;

    f32x4 acc[4][4];
    #pragma unroll
    for (int fm = 0; fm < 4; fm++)
        #pragma unroll
        for (int fn = 0; fn < 4; fn++) acc[fm][fn] = {0.f, 0.f, 0.f, 0.f};

    const int NKS = KD / 32;
    // prologue: stage K-step 0 into buf 0
    gload16(Ag0, &sA[0][w * 32][0]);
    gload16(Ag1, &sA[0][w * 32 + 16][0]);
    gload16(Bg0, &sB[0][w * 32][0]);
    gload16(Bg1, &sB[0][w * 32 + 16][0]);
    __syncthreads();

    #pragma unroll
    for (int ks = 0; ks < NKS; ks++) {
        int cur = ks & 1;
        if (ks + 1 < NKS) {          // issue next-tile loads (fly during MFMA)
            int ko = (ks + 1) * 32;
            gload16(Ag0 + ko, &sA[cur ^ 1][w * 32][0]);
            gload16(Ag1 + ko, &sA[cur ^ 1][w * 32 + 16][0]);
            gload16(Bg0 + ko, &sB[cur ^ 1][w * 32][0]);
            gload16(Bg1 + ko, &sB[cur ^ 1][w * 32 + 16][0]);
        }
        short8 af[4], bf[4];
        #pragma unroll
        for (int fm = 0; fm < 4; fm++)
            af[fm] = *(const short8*)&sA[cur][wr * 64 + fm * 16 + lq][g * 8];
        #pragma unroll
        for (int fn = 0; fn < 4; fn++)
            bf[fn] = *(const short8*)&sB[cur][wc * 64 + fn * 16 + lq][g * 8];
        #pragma unroll
        for (int fm = 0; fm < 4; fm++)
            #pragma unroll
            for (int fn = 0; fn < 4; fn++)
                acc[fm][fn] = __builtin_amdgcn_mfma_f32_16x16x32_bf16(af[fm], bf[fn], acc[fm][fn], 0, 0, 0);
        __syncthreads();             // drains vmcnt(0)+lgkmcnt(0): next buf ready
    }

    #pragma unroll
    for (int fm = 0; fm < 4; fm++) {
        int mbase = m0 + wr * 64 + fm * 16 + 4 * g;
        #pragma unroll
        for (int fn = 0; fn < 4; fn++) {
            int col = n0 + wc * 64 + fn * 16 + lq;
            float bv = bp[col];
            #pragma unroll
            for (int r = 0; r < 4; r++) {
                float o = acc[fm][fn][r] + bv;
                if (ACT) o = gelu_f(o);
                size_t off = (size_t)(mbase + r) * Nfull + col;
                if (RES) o += C[off];
                if (OF32) C[off] = o;
                if (OBF) Cb[off] = f2bf(o);
            }
        }
    }
}

// ---------------------------------------------------------------------------
// MFMA attention v4: block = (b, 32 q-rows) x 8 waves = 8 heads.
// dist slab (32x512 fp16) staged ONCE per block into LDS (coalesced), shared
// by all heads. Wave w = head w, 2 q-chunks of 16. Swapped-operand MFMA.
#define DPAD 520
__global__ __launch_bounds__(512) void attn_mfma_kernel(
    const u16* __restrict__ Qb, const u16* __restrict__ Kb, const u16* __restrict__ Vt,
    const u16* __restrict__ distT, const float* __restrict__ dens,
    const float* __restrict__ dist_raw, const float* __restrict__ dens_raw,
    u16* __restrict__ O) {
    __shared__ u16 sD[32][DPAD];
    __shared__ u16 sP[16][512];          // [wave*2+chunk][16q x 32s]
    int blk = blockIdx.x;                // b*128 + kt
    int kt = blk & 127, b = blk >> 7;
    int t = threadIdx.x;
    {   // stage dist rows kt*32..kt*32+31 (coalesced 64B/thread)
        int r = t >> 4, cs = (t & 15) * 32;
        const u16* gp = distT + ((size_t)(b * KGRID) + kt * 32 + r) * SSRC + cs;
        uint4 d0 = *(const uint4*)gp;
        uint4 d1 = *(const uint4*)(gp + 8);
        uint4 d2 = *(const uint4*)(gp + 16);
        uint4 d3 = *(const uint4*)(gp + 24);
        *(uint4*)&sD[r][cs] = d0;
        *(uint4*)&sD[r][cs + 8] = d1;
        *(uint4*)&sD[r][cs + 16] = d2;
        *(uint4*)&sD[r][cs + 24] = d3;
    }
    __syncthreads();

    int w = t >> 6, lane = t & 63, lq = lane & 15, g = lane >> 4;
    int h = w;
    const float LOG2E = 1.4426950408889634f;
    float th = tanhf(dens_raw[0]);
    float c1 = log1pf(__expf(dist_raw[0]));
    float gs[2], gc[2];
    short8 qf[2];
    #pragma unroll
    for (int qc = 0; qc < 2; qc++) {
        int qrow = kt * 32 + qc * 16 + lq;
        float gate = 1.0f + th * dens[b * KGRID + qrow];
        gs[qc] = gate * ATT_SCALE * LOG2E;
        gc[qc] = gate * c1 * LOG2E;
        qf[qc] = *(const short8*)(Qb + (size_t)(b * KGRID + qrow) * DD + h * HDIM + g * 8);
    }
    const u16* kbase = Kb + (size_t)b * SSRC * DD + h * HDIM + g * 8;
    const u16* vbase = Vt + ((size_t)(b * NHEADS + h) * HDIM + lq) * SSRC + g * 8;

    f32x4 accA[2] = {{0.f, 0.f, 0.f, 0.f}, {0.f, 0.f, 0.f, 0.f}};
    f32x4 accB[2] = {{0.f, 0.f, 0.f, 0.f}, {0.f, 0.f, 0.f, 0.f}};
    f32x4 zero = {0.f, 0.f, 0.f, 0.f};
    float lsum[2] = {0.f, 0.f};

    for (int s0 = 0; s0 < SSRC; s0 += 32) {
        #pragma unroll
        for (int tl = 0; tl < 2; tl++) {
            int sb = s0 + tl * 16;
            short8 kf = *(const short8*)(kbase + (size_t)(sb + lq) * DD);
            #pragma unroll
            for (int qc = 0; qc < 2; qc++) {
                f32x4 c = __builtin_amdgcn_mfma_f32_16x16x32_bf16(kf, qf[qc], zero, 0, 0, 0);
                uint2 dh = *(const uint2*)&sD[qc * 16 + lq][sb + 4 * g];
                float p0 = exp2f(gs[qc] * c[0] - gc[qc] * h2f(dh.x));
                float p1 = exp2f(gs[qc] * c[1] - gc[qc] * h2f(dh.x >> 16));
                float p2 = exp2f(gs[qc] * c[2] - gc[qc] * h2f(dh.y));
                float p3 = exp2f(gs[qc] * c[3] - gc[qc] * h2f(dh.y >> 16));
                lsum[qc] += (p0 + p1) + (p2 + p3);
                int idx = lq * 32 + tl * 16 + 4 * g;
                *(unsigned int*)&sP[w * 2 + qc][idx]     = cvtpk_bf16(p0, p1);
                *(unsigned int*)&sP[w * 2 + qc][idx + 2] = cvtpk_bf16(p2, p3);
            }
        }
        short8 v0 = *(const short8*)(vbase + s0);
        short8 v1 = *(const short8*)(vbase + 16 * SSRC + s0);
        #pragma unroll
        for (int qc = 0; qc < 2; qc++) {
            short8 pf = *(const short8*)&sP[w * 2 + qc][lq * 32 + g * 8];
            accA[qc] = __builtin_amdgcn_mfma_f32_16x16x32_bf16(v0, pf, accA[qc], 0, 0, 0);
            accB[qc] = __builtin_amdgcn_mfma_f32_16x16x32_bf16(v1, pf, accB[qc], 0, 0, 0);
        }
    }

    #pragma unroll
    for (int qc = 0; qc < 2; qc++) {
        float ls = lsum[qc];
        ls += __shfl_xor(ls, 16, 64);
        ls += __shfl_xor(ls, 32, 64);
        float inv = 1.0f / ls;
        int qrow = kt * 32 + qc * 16 + lq;
        u16* op = O + (size_t)(b * KGRID + qrow) * DD + h * HDIM + 4 * g;
        uint2 o0, o1;
        o0.x = cvtpk_bf16(accA[qc][0] * inv, accA[qc][1] * inv);
        o0.y = cvtpk_bf16(accA[qc][2] * inv, accA[qc][3] * inv);
        o1.x = cvtpk_bf16(accB[qc][0] * inv, accB[qc][1] * inv);
        o1.y = cvtpk_bf16(accB[qc][2] * inv, accB[qc][3] * inv);
        *(uint2*)op = o0;
        *(uint2*)(op + 16) = o1;
    }
}

// ---------------------------------------------------------------------------
__global__ void head_kernel(const float* __restrict__ tf, const float* __restrict__ hW,
                            const float* __restrict__ hb, float* __restrict__ out) {
    int w = threadIdx.x >> 6, lane = threadIdx.x & 63;
    int idx = blockIdx.x * 4 + w;
    float4 x = ((const float4*)tf)[(size_t)idx * 64 + lane];
    float4 ww = ((const float4*)hW)[lane];
    float s = x.x * ww.x + x.y * ww.y + x.z * ww.z + x.w * ww.w;
    #pragma unroll
    for (int o = 1; o < 64; o <<= 1) s += __shfl_xor(s, o, 64);
    if (lane == 0) out[idx] = s + hb[0];
}

// ---------------------------------------------------------------------------
extern "C" void kernel_launch(void* const* d_in, const int* in_sizes, int n_in,
                              void* d_out, int out_size, void* d_ws, size_t ws_size,
                              hipStream_t stream) {
    const float* meas_xy = (const float*)d_in[0];
    const float* meas_v  = (const float*)d_in[1];
    const float* bs_xy   = (const float*)d_in[2];
    const float* city    = (const float*)d_in[3];
    const float* meas_W  = (const float*)d_in[4];
    const float* meas_b  = (const float*)d_in[5];
    const float* pW1     = (const float*)d_in[6];
    const float* pb1     = (const float*)d_in[7];
    const float* pW2     = (const float*)d_in[8];
    const float* pb2     = (const float*)d_in[9];
    const float* bs_W    = (const float*)d_in[10];
    const float* bs_b    = (const float*)d_in[11];
    const float* task_emb= (const float*)d_in[12];
    const float* taskp_W = (const float*)d_in[13];
    const float* taskp_b = (const float*)d_in[14];
    const float* grid_pos= (const float*)d_in[15];
    const float* lnq_g   = (const float*)d_in[16];
    const float* lnq_b   = (const float*)d_in[17];
    const float* lnkv_g  = (const float*)d_in[18];
    const float* lnkv_b  = (const float*)d_in[19];
    const float* qW      = (const float*)d_in[20];
    const float* qb      = (const float*)d_in[21];
    const float* kW      = (const float*)d_in[22];
    const float* kb      = (const float*)d_in[23];
    const float* vW      = (const float*)d_in[24];
    const float* vb      = (const float*)d_in[25];
    const float* oW      = (const float*)d_in[26];
    const float* ob      = (const float*)d_in[27];
    const float* dist_raw= (const float*)d_in[28];
    const float* dens_raw= (const float*)d_in[29];
    const float* lnf_g   = (const float*)d_in[30];
    const float* lnf_b   = (const float*)d_in[31];
    const float* f1W     = (const float*)d_in[32];
    const float* f1b     = (const float*)d_in[33];
    const float* f2W     = (const float*)d_in[34];
    const float* f2b     = (const float*)d_in[35];
    const float* tfp_W   = (const float*)d_in[36];
    const float* tfp_b   = (const float*)d_in[37];
    const float* head_W  = (const float*)d_in[38];
    const float* head_b  = (const float*)d_in[39];
    const int*   task_id = (const int*)d_in[40];

    float* ws = (float*)d_ws;
    float* src   = ws;                       // 524288
    float* gridb = src + 524288;             // 4194304
    float* tmp1  = gridb + 4194304;          // 4194304 (task-gemm fp32 out; distT aliases)
    float* sxyb  = tmp1 + 4194304;           // 4096
    float* densb = sxyb + 4096;              // 16384
    float* tvec  = densb + 16384;            // 1024

    // distT aliases tmp1 (8.4M u16 == 4.2M floats). tmp1 is written only by the
    // final task gemm, after the last attn read of distT.
    u16* distT = (u16*)tmp1;

    u16* wtq  = (u16*)(tvec + 1024);         // 131072 (2 layers)
    u16* wtk  = wtq  + 131072;
    u16* wtv  = wtk  + 131072;
    u16* wto  = wtv  + 131072;
    u16* wtf1 = wto  + 131072;               // 262144
    u16* wtf2 = wtf1 + 262144;               // 262144
    u16* wtt  = wtf2 + 262144;               // 262144
    u16* kvbf = wtt  + 262144;               // 524288
    u16* lnbf = kvbf + 524288;               // 4194304
    u16* qbf  = lnbf + 4194304;              // 4194304
    u16* kbf  = qbf  + 4194304;              // 524288
    u16* vbf  = kbf  + 524288;               // 524288
    u16* vtbf = vbf  + 524288;               // 524288
    u16* obf  = vtbf + 524288;               // 4194304
    u16* fhbf = obf  + 4194304;              // 8388608

    const dim3 B32x8(32, 8);

    task_vec_kernel<<<BB, 256, 0, stream>>>(task_emb, taskp_W, taskp_b, task_id, tvec);
    grid_init_kernel<<<4096, 256, 0, stream>>>(grid_pos, tvec, gridb);
    src_build_kernel<<<BB * SSRC, 256, 0, stream>>>(meas_xy, meas_v, bs_xy, city,
                                                    meas_W, meas_b, pW1, pb1, pW2, pb2,
                                                    bs_W, bs_b, src, sxyb);
    density_kernel<<<4096, 256, 0, stream>>>(meas_xy, densb);
    dist_kernel<<<BB * KGRID, 256, 0, stream>>>(sxyb, distT);

    wconv_kernel<<<dim3(8, 8, 2), B32x8, 0, stream>>>(qW, wtq, 256, 256);
    wconv_kernel<<<dim3(8, 8, 2), B32x8, 0, stream>>>(kW, wtk, 256, 256);
    wconv_kernel<<<dim3(8, 8, 2), B32x8, 0, stream>>>(vW, wtv, 256, 256);
    wconv_kernel<<<dim3(8, 8, 2), B32x8, 0, stream>>>(oW, wto, 256, 256);
    wconv_kernel<<<dim3(16, 8, 2), B32x8, 0, stream>>>(f1W, wtf1, 256, 512);
    wconv_kernel<<<dim3(8, 16, 2), B32x8, 0, stream>>>(f2W, wtf2, 512, 256);
    wconv_kernel<<<dim3(8, 8, 4), B32x8, 0, stream>>>(tfp_W, wtt, 256, 256);

    for (int i = 0; i < NLAYERS; i++) {
        const int w16 = i * 65536, bso = i * DD;
        ln_kernel<<<512, 256, 0, stream>>>(src, lnkv_g + bso, lnkv_b + bso, kvbf, 2048);
        gemm_glds<0, 0, 1, 0, 0, 256><<<dim3(16, 2), 256, 0, stream>>>(
            kvbf, wtk + w16, kb + bso, tmp1, kbf, 256, nullptr, 0, 0);
        gemm_glds<0, 0, 1, 0, 0, 256><<<dim3(16, 2), 256, 0, stream>>>(
            kvbf, wtv + w16, vb + bso, tmp1, vbf, 256, nullptr, 0, 0);
        vtrans_kernel<<<dim3(8, 16, 4), B32x8, 0, stream>>>(vbf, vtbf);
        ln_kernel<<<4096, 256, 0, stream>>>(gridb, lnq_g + bso, lnq_b + bso, lnbf, 16384);
        gemm_glds<0, 0, 1, 0, 0, 256><<<dim3(128, 2), 256, 0, stream>>>(
            lnbf, wtq + w16, qb + bso, tmp1, qbf, 256, nullptr, 0, 0);
        attn_mfma_kernel<<<BB * (KGRID / 32), 512, 0, stream>>>(
            qbf, kbf, vtbf, distT, densb, dist_raw + i, dens_raw + i, obf);
        gemm_glds<0, 1, 0, 1, 0, 256><<<dim3(128, 2), 256, 0, stream>>>(
            obf, wto + w16, ob + bso, gridb, obf, 256, nullptr, 0, 0);
        ln_kernel<<<4096, 256, 0, stream>>>(gridb, lnf_g + bso, lnf_b + bso, lnbf, 16384);
        gemm_glds<1, 0, 1, 0, 0, 256><<<dim3(128, 4), 256, 0, stream>>>(
            lnbf, wtf1 + i * 131072, f1b + i * 512, tmp1, fhbf, 512, nullptr, 0, 0);
        gemm_glds<0, 1, 1, 1, 0, 512><<<dim3(128, 2), 256, 0, stream>>>(
            fhbf, wtf2 + i * 131072, f2b + bso, gridb, lnbf, 256, nullptr, 0, 0);
    }

    // task gemm writes tmp1 (OF32) — clobbers distT, safe: all attn reads done.
    gemm_glds<1, 0, 0, 1, 1, 256><<<dim3(128, 2), 256, 0, stream>>>(
        lnbf, wtt, tfp_b, tmp1, obf, 256, task_id, 65536, 256);
    head_kernel<<<4096, 256, 0, stream>>>(tmp1, head_W, head_b, (float*)d_out);
}

// Round 9
// 478.867 us; speedup vs baseline: 1.6849x; 1.0804x over previous
//
#include <hip/hip_runtime.h>
#include <hip/hip_fp16.h>
#include <math.h>

#define DD 256
#define NHEADS 8
#define HDIM 32
#define NLAYERS 2
#define GSZ 64
#define KGRID 4096      // GS*GS
#define TTASK 4
#define BB 4
#define NMEAS 511
#define SSRC 512        // N+1
#define HCITY 128
#define WCITY 128
#define ATT_SCALE 0.17677669529663687f   // 32^-0.5
#define INV2S2 78.125f                   // 1/(2*0.08^2)
#define LOG2E 1.4426950408889634f

typedef unsigned short u16;
typedef __attribute__((ext_vector_type(8))) short short8;
typedef __attribute__((ext_vector_type(4))) float f32x4;

__device__ __forceinline__ u16 f2bf(float f) {
    union { float f; unsigned int u; } x; x.f = f;
    return (u16)((x.u + 0x7fffu + ((x.u >> 16) & 1u)) >> 16);
}
__device__ __forceinline__ unsigned int cvtpk_bf16(float a, float b) {
    unsigned int r;
    asm("v_cvt_pk_bf16_f32 %0, %1, %2" : "=v"(r) : "v"(a), "v"(b));
    return r;
}
__device__ __forceinline__ float h2f(unsigned int u) {
    float r;
    asm("v_cvt_f32_f16 %0, %1" : "=v"(r) : "v"(u));
    return r;
}
__device__ __forceinline__ float gelu_f(float x) {
    return 0.5f * x * (1.0f + erff(x * 0.7071067811865476f));
}
// async global->LDS, 16B/lane; LDS dest = wave-uniform base + 16*lane.
__device__ __forceinline__ void gload16(const u16* g, u16* l) {
    __builtin_amdgcn_global_load_lds(
        (__attribute__((address_space(1))) void*)g,
        (__attribute__((address_space(3))) void*)l, 16, 0, 0);
}

// ---------------------------------------------------------------------------
__global__ void task_vec_kernel(const float* __restrict__ task_emb,
                                const float* __restrict__ tpW,
                                const float* __restrict__ tpb,
                                const int* __restrict__ task_id,
                                float* __restrict__ tv) {
    int b = blockIdx.x, t = threadIdx.x;
    int id = task_id[b];
    float a = tpb[t];
    for (int e = 0; e < DD; e++) a = fmaf(task_emb[id * DD + e], tpW[e * DD + t], a);
    tv[b * DD + t] = a;
}

__global__ void grid_init_kernel(const float* __restrict__ grid_pos,
                                 const float* __restrict__ tv,
                                 float* __restrict__ g) {
    int f = blockIdx.x * 256 + threadIdx.x;
    int b = f >> 18;
    float4 gp = ((const float4*)grid_pos)[f & 262143];
    float4 tvv = ((const float4*)tv)[b * 64 + (f & 63)];
    float4 o; o.x = gp.x + tvv.x; o.y = gp.y + tvv.y; o.z = gp.z + tvv.z; o.w = gp.w + tvv.w;
    ((float4*)g)[f] = o;
}

// ---------------------------------------------------------------------------
__global__ __launch_bounds__(256) void src_build_kernel(
    const float* __restrict__ meas_xy, const float* __restrict__ meas_v,
    const float* __restrict__ bs_xy, const float* __restrict__ city,
    const float* __restrict__ meas_W, const float* __restrict__ meas_b,
    const float* __restrict__ pW1, const float* __restrict__ pb1,
    const float* __restrict__ pW2, const float* __restrict__ pb2,
    const float* __restrict__ bs_W, const float* __restrict__ bs_b,
    float* __restrict__ src, float* __restrict__ src_xy) {
    __shared__ float sp[81];
    __shared__ float sh[DD];
    int b = blockIdx.x / SSRC, s = blockIdx.x % SSRC, t = threadIdx.x;
    if (s < NMEAS) {
        float mx = meas_xy[(b * NMEAS + s) * 2];
        float my = meas_xy[(b * NMEAS + s) * 2 + 1];
        float mv = meas_v[b * NMEAS + s];
        int cx = (int)rintf(mx * 127.0f); cx = min(max(cx, 0), 127);
        int cy = (int)rintf(my * 127.0f); cy = min(max(cy, 0), 127);
        if (t < 81) {
            int rr = cy + t / 9 - 4, cc = cx + t % 9 - 4;
            sp[t] = (rr >= 0 && rr < HCITY && cc >= 0 && cc < WCITY)
                        ? city[(b * HCITY + rr) * WCITY + cc] : 0.0f;
        }
        __syncthreads();
        float a1 = pb1[t];
        #pragma unroll 9
        for (int e = 0; e < 81; e++) a1 = fmaf(sp[e], pW1[e * DD + t], a1);
        sh[t] = gelu_f(a1);
        __syncthreads();
        float a2 = pb2[t];
        for (int e = 0; e < DD; e++) a2 = fmaf(sh[e], pW2[e * DD + t], a2);
        float mt = mx * meas_W[t] + my * meas_W[DD + t] + mv * meas_W[2 * DD + t] + meas_b[t];
        src[((size_t)(b * SSRC + s)) * DD + t] = mt + a2;
        if (t == 0) { src_xy[(b * SSRC + s) * 2] = mx; src_xy[(b * SSRC + s) * 2 + 1] = my; }
    } else {
        float bx = bs_xy[b * 2], by = bs_xy[b * 2 + 1];
        src[((size_t)(b * SSRC + s)) * DD + t] = bx * bs_W[t] + by * bs_W[DD + t] + bs_b[t];
        if (t == 0) { src_xy[(b * SSRC + s) * 2] = bx; src_xy[(b * SSRC + s) * 2 + 1] = by; }
    }
}

// ---------------------------------------------------------------------------
__global__ void density_kernel(const float* __restrict__ meas_xy, float* __restrict__ dens) {
    int w = threadIdx.x >> 6, lane = threadIdx.x & 63;
    int idx = blockIdx.x * 4 + w;
    int b = idx >> 12, k = idx & 4095;
    float gx = ((k & 63) + 0.5f) * (1.0f / 64.0f);
    float gy = ((k >> 6) + 0.5f) * (1.0f / 64.0f);
    float s = 0.0f;
    for (int n = lane; n < NMEAS; n += 64) {
        float2 xy = ((const float2*)meas_xy)[b * NMEAS + n];
        float dx = gx - xy.x, dy = gy - xy.y;
        s += __expf(-(dx * dx + dy * dy) * INV2S2);
    }
    #pragma unroll
    for (int o = 1; o < 64; o <<= 1) s += __shfl_xor(s, o, 64);
    if (lane == 0) dens[idx] = s * (1.0f / 511.0f);
}

// ---------------------------------------------------------------------------
// params: per-layer per-query gate tables, fused kv bias, d_out init.
// gsc[l][i] = gate*SCALE*LOG2E (folded into Q rows); gcc[l][i] = gate*softplus(dist)*LOG2E.
__global__ void params_kernel(const float* __restrict__ dens,
                              const float* __restrict__ dist_raw,
                              const float* __restrict__ dens_raw,
                              const float* __restrict__ kb, const float* __restrict__ vb,
                              const float* __restrict__ hb,
                              float* __restrict__ gsc, float* __restrict__ gcc,
                              float* __restrict__ kvb, float* __restrict__ out) {
    int idx = blockIdx.x * 256 + threadIdx.x;      // 0..32767
    int l = idx >> 14, i = idx & 16383;
    float gate = 1.0f + tanhf(dens_raw[l]) * dens[i];
    gsc[idx] = gate * ATT_SCALE * LOG2E;
    gcc[idx] = gate * log1pf(__expf(dist_raw[l])) * LOG2E;
    if (idx < 16384) out[idx] = hb[0];
    if (idx < 1024) {
        int ll = idx >> 9, c = idx & 511;
        kvb[idx] = (c < 256) ? kb[ll * 256 + c] : vb[ll * 256 + c - 256];
    }
}

// ---------------------------------------------------------------------------
// dist table: dt[b][k][s] = |gxy_k - src_xy[b][s]| fp16 (RNE). 16.7 MB.
__global__ __launch_bounds__(256) void dist_kernel(const float* __restrict__ sxy_g,
                                                   u16* __restrict__ dt) {
    __shared__ float2 sxy[SSRC];
    int bk = blockIdx.x;
    int b = bk >> 12, k = bk & 4095;
    int t = threadIdx.x;
    sxy[t]       = ((const float2*)sxy_g)[b * SSRC + t];
    sxy[t + 256] = ((const float2*)sxy_g)[b * SSRC + t + 256];
    __syncthreads();
    float gx = ((k & 63) + 0.5f) * (1.0f / 64.0f);
    float gy = ((k >> 6) + 0.5f) * (1.0f / 64.0f);
    float2 p0 = sxy[2 * t], p1 = sxy[2 * t + 1];
    float dx0 = gx - p0.x, dy0 = gy - p0.y;
    float dx1 = gx - p1.x, dy1 = gy - p1.y;
    float d0 = sqrtf(dx0 * dx0 + dy0 * dy0);
    float d1 = sqrtf(dx1 * dx1 + dy1 * dy1);
    __half h0 = __float2half(d0), h1 = __float2half(d1);
    unsigned int pk = (unsigned int)__half_as_ushort(h0) |
                      ((unsigned int)__half_as_ushort(h1) << 16);
    ((unsigned int*)dt)[(size_t)bk * 256 + t] = pk;
}

// ---------------------------------------------------------------------------
__global__ void ln_kernel(const float* __restrict__ X, const float* __restrict__ g,
                          const float* __restrict__ bvec, u16* __restrict__ Yb, int rows) {
    int w = threadIdx.x >> 6, lane = threadIdx.x & 63;
    int row = blockIdx.x * 4 + w;
    if (row >= rows) return;
    float4 x = ((const float4*)X)[(size_t)row * 64 + lane];
    float s = x.x + x.y + x.z + x.w;
    float q = x.x * x.x + x.y * x.y + x.z * x.z + x.w * x.w;
    #pragma unroll
    for (int o = 1; o < 64; o <<= 1) { s += __shfl_xor(s, o, 64); q += __shfl_xor(q, o, 64); }
    float m = s * (1.0f / 256.0f);
    float v = q * (1.0f / 256.0f) - m * m;
    float rs = rsqrtf(v + 1e-5f);
    float4 gg = ((const float4*)g)[lane], bb = ((const float4*)bvec)[lane];
    float4 y;
    y.x = (x.x - m) * rs * gg.x + bb.x;
    y.y = (x.y - m) * rs * gg.y + bb.y;
    y.z = (x.z - m) * rs * gg.z + bb.z;
    y.w = (x.w - m) * rs * gg.w + bb.w;
    uint2 o2;
    o2.x = cvtpk_bf16(y.x, y.y);
    o2.y = cvtpk_bf16(y.z, y.w);
    *(uint2*)&Yb[(size_t)row * 256 + lane * 4] = o2;
}

// ---------------------------------------------------------------------------
// Weight convert: W[z][Kd][Nd] fp32 -> Wt[z*ostride + (noff+n)*Kd + k] bf16.
__global__ __launch_bounds__(256) void wconv_kernel(const float* __restrict__ W,
                                                    u16* __restrict__ Wt, int Kd, int Nd,
                                                    int ostride, int noff) {
    __shared__ float L[32][33];
    int z = blockIdx.z;
    size_t zin = (size_t)z * Kd * Nd;
    int n0 = blockIdx.x * 32, k0 = blockIdx.y * 32;
    int tx = threadIdx.x, ty = threadIdx.y;
    #pragma unroll
    for (int yy = 0; yy < 4; yy++)
        L[tx][ty + 8 * yy] = W[zin + (size_t)(k0 + ty + 8 * yy) * Nd + n0 + tx];
    __syncthreads();
    #pragma unroll
    for (int yy = 0; yy < 4; yy++)
        Wt[(size_t)z * ostride + (size_t)(noff + n0 + ty + 8 * yy) * Kd + k0 + tx] =
            f2bf(L[ty + 8 * yy][tx]);
}

// V transpose: V[(b*512+s)*instride + inoff + n] bf16 -> Vt[(b*256+n)][512] bf16.
__global__ __launch_bounds__(256) void vtrans_kernel(const u16* __restrict__ V,
                                                     u16* __restrict__ Vt,
                                                     int instride, int inoff) {
    __shared__ u16 L[32][33];
    int b = blockIdx.z;
    int n0 = blockIdx.x * 32, s0 = blockIdx.y * 32;
    int tx = threadIdx.x, ty = threadIdx.y;
    #pragma unroll
    for (int yy = 0; yy < 4; yy++)
        L[tx][ty + 8 * yy] = V[(size_t)(b * SSRC + s0 + ty + 8 * yy) * instride + inoff + n0 + tx];
    __syncthreads();
    #pragma unroll
    for (int yy = 0; yy < 4; yy++)
        Vt[(size_t)(b * DD + n0 + ty + 8 * yy) * SSRC + s0 + tx] = L[ty + 8 * yy][tx];
}

// ---------------------------------------------------------------------------
// m97-style bf16 MFMA GEMM. Tile 128x128, BK=32, 4 waves (64x64 each, 4x4 frags),
// global_load_lds staging, double-buffered. Optional RS row-scale, HEAD fusion
// (per-row dot with hw + shfl-reduce + atomicAdd into C).
template <int ACT, int RES, int OBF, int OF32, int BATW, int RS, int HEAD, int KD>
__global__ __launch_bounds__(256) void gemm_glds(
    const u16* __restrict__ A, const u16* __restrict__ Wt,
    const float* __restrict__ bias, float* __restrict__ C, u16* __restrict__ Cb,
    int Nfull, const int* __restrict__ task_id, int wstride, int bstride,
    const float* __restrict__ rs, const float* __restrict__ hw) {
    __shared__ u16 sA[2][128][32];
    __shared__ u16 sB[2][128][32];
    int t = threadIdx.x;
    int w = t >> 6, lane = t & 63, lq = lane & 15, g = lane >> 4;
    int wr = w >> 1, wc = w & 1;
    int m0 = blockIdx.x * 128, n0 = blockIdx.y * 128;
    const u16* Wp = Wt;
    const float* bp = bias;
    if (BATW) {
        int id = task_id[m0 / KGRID];
        Wp += (size_t)id * wstride;
        bp += (size_t)id * bstride;
    }
    int srow = lane >> 2;
    int scol = (lane & 3) * 8;
    const u16* Ag0 = A  + (size_t)(m0 + w * 32 + srow) * KD + scol;
    const u16* Ag1 = Ag0 + (size_t)16 * KD;
    const u16* Bg0 = Wp + (size_t)(n0 + w * 32 + srow) * KD + scol;
    const u16* Bg1 = Bg0 + (size_t)16 * KD;

    f32x4 acc[4][4];
    #pragma unroll
    for (int fm = 0; fm < 4; fm++)
        #pragma unroll
        for (int fn = 0; fn < 4; fn++) acc[fm][fn] = {0.f, 0.f, 0.f, 0.f};

    const int NKS = KD / 32;
    gload16(Ag0, &sA[0][w * 32][0]);
    gload16(Ag1, &sA[0][w * 32 + 16][0]);
    gload16(Bg0, &sB[0][w * 32][0]);
    gload16(Bg1, &sB[0][w * 32 + 16][0]);
    __syncthreads();

    #pragma unroll
    for (int ks = 0; ks < NKS; ks++) {
        int cur = ks & 1;
        if (ks + 1 < NKS) {
            int ko = (ks + 1) * 32;
            gload16(Ag0 + ko, &sA[cur ^ 1][w * 32][0]);
            gload16(Ag1 + ko, &sA[cur ^ 1][w * 32 + 16][0]);
            gload16(Bg0 + ko, &sB[cur ^ 1][w * 32][0]);
            gload16(Bg1 + ko, &sB[cur ^ 1][w * 32 + 16][0]);
        }
        short8 af[4], bf[4];
        #pragma unroll
        for (int fm = 0; fm < 4; fm++)
            af[fm] = *(const short8*)&sA[cur][wr * 64 + fm * 16 + lq][g * 8];
        #pragma unroll
        for (int fn = 0; fn < 4; fn++)
            bf[fn] = *(const short8*)&sB[cur][wc * 64 + fn * 16 + lq][g * 8];
        #pragma unroll
        for (int fm = 0; fm < 4; fm++)
            #pragma unroll
            for (int fn = 0; fn < 4; fn++)
                acc[fm][fn] = __builtin_amdgcn_mfma_f32_16x16x32_bf16(af[fm], bf[fn], acc[fm][fn], 0, 0, 0);
        __syncthreads();
    }

    float hWv[4], bv[4];
    #pragma unroll
    for (int fn = 0; fn < 4; fn++) {
        int col = n0 + wc * 64 + fn * 16 + lq;
        bv[fn] = bp[col];
        if (HEAD) hWv[fn] = hw[col];
    }
    #pragma unroll
    for (int fm = 0; fm < 4; fm++) {
        int mbase = m0 + wr * 64 + fm * 16 + 4 * g;
        if (HEAD) {
            #pragma unroll
            for (int r = 0; r < 4; r++) {
                float part = 0.0f;
                #pragma unroll
                for (int fn = 0; fn < 4; fn++) {
                    float o = acc[fm][fn][r] + bv[fn];
                    if (ACT) o = gelu_f(o);
                    part = fmaf(o, hWv[fn], part);
                }
                part += __shfl_xor(part, 1, 64);
                part += __shfl_xor(part, 2, 64);
                part += __shfl_xor(part, 4, 64);
                part += __shfl_xor(part, 8, 64);
                if (lq == 0) atomicAdd(&C[mbase + r], part);
            }
        } else {
            #pragma unroll
            for (int fn = 0; fn < 4; fn++) {
                int col = n0 + wc * 64 + fn * 16 + lq;
                #pragma unroll
                for (int r = 0; r < 4; r++) {
                    float o = acc[fm][fn][r] + bv[fn];
                    if (RS) o *= rs[mbase + r];
                    if (ACT) o = gelu_f(o);
                    size_t off = (size_t)(mbase + r) * Nfull + col;
                    if (RES) o += C[off];
                    if (OF32) C[off] = o;
                    if (OBF) Cb[off] = f2bf(o);
                }
            }
        }
    }
}

// ---------------------------------------------------------------------------
// MFMA attention v5: Q pre-scaled by gate*SCALE*LOG2E; gc from table; dist slab
// in LDS; sP padded to 40 u16/row (16B-aligned, ~4-way instead of 8-way).
// Block = (b, 32 q) x 8 waves = 8 heads. K read from fused kvo (stride 512).
#define DPAD 520
#define PSTR 40
__global__ __launch_bounds__(512) void attn_mfma_kernel(
    const u16* __restrict__ Qb, const u16* __restrict__ KVo, const u16* __restrict__ Vt,
    const u16* __restrict__ distT, const float* __restrict__ gccL,
    u16* __restrict__ O) {
    __shared__ u16 sD[32][DPAD];
    __shared__ u16 sP[16][16 * PSTR];
    int blk = blockIdx.x;                // b*128 + kt
    int kt = blk & 127, b = blk >> 7;
    int t = threadIdx.x;
    {   // stage dist rows (coalesced 64B/thread)
        int r = t >> 4, cs = (t & 15) * 32;
        const u16* gp = distT + ((size_t)(b * KGRID) + kt * 32 + r) * SSRC + cs;
        uint4 d0 = *(const uint4*)gp;
        uint4 d1 = *(const uint4*)(gp + 8);
        uint4 d2 = *(const uint4*)(gp + 16);
        uint4 d3 = *(const uint4*)(gp + 24);
        *(uint4*)&sD[r][cs] = d0;
        *(uint4*)&sD[r][cs + 8] = d1;
        *(uint4*)&sD[r][cs + 16] = d2;
        *(uint4*)&sD[r][cs + 24] = d3;
    }
    __syncthreads();

    int w = t >> 6, lane = t & 63, lq = lane & 15, g = lane >> 4;
    int h = w;
    float gc[2];
    short8 qf[2];
    #pragma unroll
    for (int qc = 0; qc < 2; qc++) {
        int qrow = kt * 32 + qc * 16 + lq;
        gc[qc] = gccL[b * KGRID + qrow];
        qf[qc] = *(const short8*)(Qb + (size_t)(b * KGRID + qrow) * DD + h * HDIM + g * 8);
    }
    const u16* kbase = KVo + (size_t)(b * SSRC) * 512 + h * HDIM + g * 8;
    const u16* vbase = Vt + ((size_t)(b * NHEADS + h) * HDIM + lq) * SSRC + g * 8;

    f32x4 accA[2] = {{0.f, 0.f, 0.f, 0.f}, {0.f, 0.f, 0.f, 0.f}};
    f32x4 accB[2] = {{0.f, 0.f, 0.f, 0.f}, {0.f, 0.f, 0.f, 0.f}};
    f32x4 zero = {0.f, 0.f, 0.f, 0.f};
    float lsum[2] = {0.f, 0.f};

    for (int s0 = 0; s0 < SSRC; s0 += 32) {
        #pragma unroll
        for (int tl = 0; tl < 2; tl++) {
            int sb = s0 + tl * 16;
            short8 kf = *(const short8*)(kbase + (size_t)(sb + lq) * 512);
            #pragma unroll
            for (int qc = 0; qc < 2; qc++) {
                f32x4 c = __builtin_amdgcn_mfma_f32_16x16x32_bf16(kf, qf[qc], zero, 0, 0, 0);
                uint2 dh = *(const uint2*)&sD[qc * 16 + lq][sb + 4 * g];
                float p0 = exp2f(fmaf(-gc[qc], h2f(dh.x), c[0]));
                float p1 = exp2f(fmaf(-gc[qc], h2f(dh.x >> 16), c[1]));
                float p2 = exp2f(fmaf(-gc[qc], h2f(dh.y), c[2]));
                float p3 = exp2f(fmaf(-gc[qc], h2f(dh.y >> 16), c[3]));
                lsum[qc] += (p0 + p1) + (p2 + p3);
                int idx = lq * PSTR + tl * 16 + 4 * g;
                *(unsigned int*)&sP[w * 2 + qc][idx]     = cvtpk_bf16(p0, p1);
                *(unsigned int*)&sP[w * 2 + qc][idx + 2] = cvtpk_bf16(p2, p3);
            }
        }
        short8 v0 = *(const short8*)(vbase + s0);
        short8 v1 = *(const short8*)(vbase + 16 * SSRC + s0);
        #pragma unroll
        for (int qc = 0; qc < 2; qc++) {
            short8 pf = *(const short8*)&sP[w * 2 + qc][lq * PSTR + g * 8];
            accA[qc] = __builtin_amdgcn_mfma_f32_16x16x32_bf16(v0, pf, accA[qc], 0, 0, 0);
            accB[qc] = __builtin_amdgcn_mfma_f32_16x16x32_bf16(v1, pf, accB[qc], 0, 0, 0);
        }
    }

    #pragma unroll
    for (int qc = 0; qc < 2; qc++) {
        float ls = lsum[qc];
        ls += __shfl_xor(ls, 16, 64);
        ls += __shfl_xor(ls, 32, 64);
        float inv = 1.0f / ls;
        int qrow = kt * 32 + qc * 16 + lq;
        u16* op = O + (size_t)(b * KGRID + qrow) * DD + h * HDIM + 4 * g;
        uint2 o0, o1;
        o0.x = cvtpk_bf16(accA[qc][0] * inv, accA[qc][1] * inv);
        o0.y = cvtpk_bf16(accA[qc][2] * inv, accA[qc][3] * inv);
        o1.x = cvtpk_bf16(accB[qc][0] * inv, accB[qc][1] * inv);
        o1.y = cvtpk_bf16(accB[qc][2] * inv, accB[qc][3] * inv);
        *(uint2*)op = o0;
        *(uint2*)(op + 16) = o1;
    }
}

// ---------------------------------------------------------------------------
extern "C" void kernel_launch(void* const* d_in, const int* in_sizes, int n_in,
                              void* d_out, int out_size, void* d_ws, size_t ws_size,
                              hipStream_t stream) {
    const float* meas_xy = (const float*)d_in[0];
    const float* meas_v  = (const float*)d_in[1];
    const float* bs_xy   = (const float*)d_in[2];
    const float* city    = (const float*)d_in[3];
    const float* meas_W  = (const float*)d_in[4];
    const float* meas_b  = (const float*)d_in[5];
    const float* pW1     = (const float*)d_in[6];
    const float* pb1     = (const float*)d_in[7];
    const float* pW2     = (const float*)d_in[8];
    const float* pb2     = (const float*)d_in[9];
    const float* bs_W    = (const float*)d_in[10];
    const float* bs_b    = (const float*)d_in[11];
    const float* task_emb= (const float*)d_in[12];
    const float* taskp_W = (const float*)d_in[13];
    const float* taskp_b = (const float*)d_in[14];
    const float* grid_pos= (const float*)d_in[15];
    const float* lnq_g   = (const float*)d_in[16];
    const float* lnq_b   = (const float*)d_in[17];
    const float* lnkv_g  = (const float*)d_in[18];
    const float* lnkv_b  = (const float*)d_in[19];
    const float* qW      = (const float*)d_in[20];
    const float* qb      = (const float*)d_in[21];
    const float* kW      = (const float*)d_in[22];
    const float* kb      = (const float*)d_in[23];
    const float* vW      = (const float*)d_in[24];
    const float* vb      = (const float*)d_in[25];
    const float* oW      = (const float*)d_in[26];
    const float* ob      = (const float*)d_in[27];
    const float* dist_raw= (const float*)d_in[28];
    const float* dens_raw= (const float*)d_in[29];
    const float* lnf_g   = (const float*)d_in[30];
    const float* lnf_b   = (const float*)d_in[31];
    const float* f1W     = (const float*)d_in[32];
    const float* f1b     = (const float*)d_in[33];
    const float* f2W     = (const float*)d_in[34];
    const float* f2b     = (const float*)d_in[35];
    const float* tfp_W   = (const float*)d_in[36];
    const float* tfp_b   = (const float*)d_in[37];
    const float* head_W  = (const float*)d_in[38];
    const float* head_b  = (const float*)d_in[39];
    const int*   task_id = (const int*)d_in[40];

    float* ws = (float*)d_ws;
    float* src   = ws;                       // 524288
    float* gridb = src + 524288;             // 4194304
    float* distTf= gridb + 4194304;          // 4194304 (fp16 dist table lives here)
    float* sxyb  = distTf + 4194304;         // 4096
    float* densb = sxyb + 4096;              // 16384
    float* tvec  = densb + 16384;            // 1024
    float* gsc   = tvec + 1024;              // 32768 (2 layers x 16384)
    float* gcc   = gsc + 32768;              // 32768
    float* kvb   = gcc + 32768;              // 1024  (2 layers x 512)

    u16* distT = (u16*)distTf;

    u16* wtq  = (u16*)(kvb + 1024);          // 131072
    u16* wto  = wtq  + 131072;               // 131072
    u16* wkv  = wto  + 131072;               // 262144 (2 layers x [512][256])
    u16* wtf1 = wkv  + 262144;               // 262144
    u16* wtf2 = wtf1 + 262144;               // 262144
    u16* wtt  = wtf2 + 262144;               // 262144
    u16* kvbf = wtt  + 262144;               // 524288
    u16* lnbf = kvbf + 524288;               // 4194304
    u16* qbf  = lnbf + 4194304;              // 4194304
    u16* kvo  = qbf  + 4194304;              // 1048576 (2048 x 512: K|V)
    u16* vtbf = kvo  + 1048576;              // 524288
    u16* obf  = vtbf + 524288;               // 4194304
    u16* fhbf = obf  + 4194304;              // 8388608

    const dim3 B32x8(32, 8);

    task_vec_kernel<<<BB, 256, 0, stream>>>(task_emb, taskp_W, taskp_b, task_id, tvec);
    grid_init_kernel<<<4096, 256, 0, stream>>>(grid_pos, tvec, gridb);
    src_build_kernel<<<BB * SSRC, 256, 0, stream>>>(meas_xy, meas_v, bs_xy, city,
                                                    meas_W, meas_b, pW1, pb1, pW2, pb2,
                                                    bs_W, bs_b, src, sxyb);
    density_kernel<<<4096, 256, 0, stream>>>(meas_xy, densb);
    params_kernel<<<128, 256, 0, stream>>>(densb, dist_raw, dens_raw, kb, vb, head_b,
                                           gsc, gcc, kvb, (float*)d_out);
    dist_kernel<<<BB * KGRID, 256, 0, stream>>>(sxyb, distT);

    wconv_kernel<<<dim3(8, 8, 2), B32x8, 0, stream>>>(qW, wtq, 256, 256, 65536, 0);
    wconv_kernel<<<dim3(8, 8, 2), B32x8, 0, stream>>>(kW, wkv, 256, 256, 131072, 0);
    wconv_kernel<<<dim3(8, 8, 2), B32x8, 0, stream>>>(vW, wkv, 256, 256, 131072, 256);
    wconv_kernel<<<dim3(8, 8, 2), B32x8, 0, stream>>>(oW, wto, 256, 256, 65536, 0);
    wconv_kernel<<<dim3(16, 8, 2), B32x8, 0, stream>>>(f1W, wtf1, 256, 512, 131072, 0);
    wconv_kernel<<<dim3(8, 16, 2), B32x8, 0, stream>>>(f2W, wtf2, 512, 256, 131072, 0);
    wconv_kernel<<<dim3(8, 8, 4), B32x8, 0, stream>>>(tfp_W, wtt, 256, 256, 65536, 0);

    for (int i = 0; i < NLAYERS; i++) {
        const int w16 = i * 65536, bso = i * DD;
        ln_kernel<<<512, 256, 0, stream>>>(src, lnkv_g + bso, lnkv_b + bso, kvbf, 2048);
        // fused K|V gemm: out kvo[2048][512]
        gemm_glds<0, 0, 1, 0, 0, 0, 0, 256><<<dim3(16, 4), 256, 0, stream>>>(
            kvbf, wkv + i * 131072, kvb + i * 512, nullptr, kvo, 512, nullptr, 0, 0, nullptr, nullptr);
        vtrans_kernel<<<dim3(8, 16, 4), B32x8, 0, stream>>>(kvo, vtbf, 512, 256);
        ln_kernel<<<4096, 256, 0, stream>>>(gridb, lnq_g + bso, lnq_b + bso, lnbf, 16384);
        // Q gemm with gate*SCALE*LOG2E row-scale folded in
        gemm_glds<0, 0, 1, 0, 0, 1, 0, 256><<<dim3(128, 2), 256, 0, stream>>>(
            lnbf, wtq + w16, qb + bso, nullptr, qbf, 256, nullptr, 0, 0, gsc + i * 16384, nullptr);
        attn_mfma_kernel<<<BB * (KGRID / 32), 512, 0, stream>>>(
            qbf, kvo, vtbf, distT, gcc + i * 16384, obf);
        gemm_glds<0, 1, 0, 1, 0, 0, 0, 256><<<dim3(128, 2), 256, 0, stream>>>(
            obf, wto + w16, ob + bso, gridb, obf, 256, nullptr, 0, 0, nullptr, nullptr);
        ln_kernel<<<4096, 256, 0, stream>>>(gridb, lnf_g + bso, lnf_b + bso, lnbf, 16384);
        gemm_glds<1, 0, 1, 0, 0, 0, 0, 256><<<dim3(128, 4), 256, 0, stream>>>(
            lnbf, wtf1 + i * 131072, f1b + i * 512, nullptr, fhbf, 512, nullptr, 0, 0, nullptr, nullptr);
        gemm_glds<0, 1, 1, 1, 0, 0, 0, 512><<<dim3(128, 2), 256, 0, stream>>>(
            fhbf, wtf2 + i * 131072, f2b + bso, gridb, lnbf, 256, nullptr, 0, 0, nullptr, nullptr);
    }

    // task gemm with fused head: atomicAdd partial dots into d_out (pre-init'd
    // with head_b by params_kernel).
    gemm_glds<1, 0, 0, 0, 1, 0, 1, 256><<<dim3(128, 2), 256, 0, stream>>>(
        lnbf, wtt, tfp_b, (float*)d_out, nullptr, 256, task_id, 65536, 256, nullptr, head_W);
}